// Round 3
// baseline (1834.842 us; speedup 1.0000x reference)
//
#include <hip/hip_runtime.h>
#include <math.h>

#define HW0 32768  // 128*256 output plane

// workspace layout (floats)
static const size_t WS_SCALES = 0;                                   // 5
static const size_t WS_MEAN   = 64;                                  // 512
static const size_t WS_MAX    = 64 + 512;                            // 512
static const size_t WS_GATE   = 64 + 1024;                           // 512
static const size_t WS_L0X    = 2048;                                // 3*64*128*256
static const size_t WS_L1     = WS_L0X + (size_t)3*64*128*256;       // 3*128*64*128
static const size_t WS_L2     = WS_L1  + (size_t)3*128*64*128;       // 3*256*32*64
static const size_t WS_F0     = WS_L2  + (size_t)3*256*32*64;        // 64*128*256
static const size_t WS_F1     = WS_F0  + (size_t)64*128*256;         // 128*64*128
static const size_t WS_F2     = WS_F1  + (size_t)128*64*128;         // 256*32*64

__global__ void prep_k(const float* __restrict__ td, const float* __restrict__ ew,
                       const float* __restrict__ eb, float* __restrict__ scales) {
  int i = threadIdx.x;
  if (i < 5) {
    float e = tanhf(ew[0] * (1.0f / (td[i] + 0.1f)) + eb[0]) + 1.0f;
    // images fed to conv0: [x0, x1, x2, h0, h1] get [enw0, enw3, enw4, enw1, enw2]
    const int slot[5] = {0, 3, 4, 1, 2};
    scales[slot[i]] = e;
  }
}

// 3x3 stride-2 pad-1 conv + bias + relu, optional per-image input scale.
// Block: 256 thr = 64 lanes x 4 groups; each thread: CPT out-channels x 2 pixels.
// SPLIT_H=0: pixels (ho, wo) and (ho, wo+64).  SPLIT_H=1: (ho, wo) and (ho+1, wo).
template <int CIN, int CPT, int SPLIT_H>
__global__ __launch_bounds__(256) void conv3x3s2_k(
    const float* __restrict__ in, const float* __restrict__ wgt,
    const float* __restrict__ bias, float* __restrict__ out,
    const float* __restrict__ scales, int Cout, int Hin, int Win) {
  constexpr int COB = CPT * 4;
  const int Hout = Hin >> 1, Wout = Win >> 1;
  const int tid = threadIdx.x;
  const int lane = tid & 63;
  const int grp = tid >> 6;
  const int nCo = Cout / COB;
  const int n  = blockIdx.z / nCo;
  const int cb = (blockIdx.z % nCo) * COB;

  __shared__ float wlds[CIN * 9 * COB];  // [ci*9+k][co_sub]
  {
    const float* wg = wgt + (size_t)cb * CIN * 9;
    const int WTOT = CIN * 9 * COB;
    for (int idx = tid; idx < WTOT; idx += 256) {
      int cs = idx / (CIN * 9);
      int rk = idx - cs * (CIN * 9);
      wlds[rk * COB + cs] = wg[(size_t)cs * (CIN * 9) + rk];
    }
  }
  __syncthreads();

  int ho0, wo0;
  if (SPLIT_H) { ho0 = blockIdx.y * 2;  wo0 = blockIdx.x * 64 + lane; }
  else         { ho0 = blockIdx.y;      wo0 = blockIdx.x * 128 + lane; }

  float acc0[CPT], acc1[CPT];
#pragma unroll
  for (int j = 0; j < CPT; ++j) { acc0[j] = 0.f; acc1[j] = 0.f; }

  const float* inn = in + (size_t)n * CIN * Hin * Win;
  const int ix_base = 2 * wo0 - 1;

  for (int ci = 0; ci < CIN; ++ci) {
    const float* ip = inn + (size_t)ci * Hin * Win;
    const float* wk = &wlds[ci * 9 * COB + grp * CPT];
#pragma unroll
    for (int ky = 0; ky < 3; ++ky) {
      const int iy = 2 * ho0 + ky - 1;
      const float* row = ip + (ptrdiff_t)iy * Win;
#pragma unroll
      for (int kx = 0; kx < 3; ++kx) {
        const int ix = ix_base + kx;
        float v0, v1;
        if (SPLIT_H) {
          const bool okx = (ix >= 0);
          v0 = (okx && iy >= 0) ? row[ix] : 0.f;           // row ho0
          v1 = okx ? row[2 * Win + ix] : 0.f;              // row ho0+1 (iy+2 always valid)
        } else {
          if (iy >= 0) {
            v0 = (ix >= 0) ? row[ix] : 0.f;
            v1 = row[ix + 128];                            // wo+64 pixel, always in range
          } else { v0 = 0.f; v1 = 0.f; }
        }
        const float* wp = wk + (ky * 3 + kx) * COB;
        float wv[CPT];
        if constexpr (CPT == 4) {
          float4 t = *(const float4*)wp;
          wv[0] = t.x; wv[1] = t.y; wv[2] = t.z; wv[3] = t.w;
        } else {
          float2 t = *(const float2*)wp;
          wv[0] = t.x; wv[1] = t.y;
        }
#pragma unroll
        for (int j = 0; j < CPT; ++j) { acc0[j] += v0 * wv[j]; acc1[j] += v1 * wv[j]; }
      }
    }
  }

  const float sc = scales ? scales[n] : 1.0f;
  const int co0 = cb + grp * CPT;
#pragma unroll
  for (int j = 0; j < CPT; ++j) {
    const float b = bias[co0 + j];
    const size_t base = (size_t)(n * Cout + co0 + j) * Hout;
    if (SPLIT_H) {
      out[(base + ho0)     * Wout + wo0] = fmaxf(acc0[j] * sc + b, 0.f);
      out[(base + ho0 + 1) * Wout + wo0] = fmaxf(acc1[j] * sc + b, 0.f);
    } else {
      out[(base + ho0) * Wout + wo0]      = fmaxf(acc0[j] * sc + b, 0.f);
      out[(base + ho0) * Wout + wo0 + 64] = fmaxf(acc1[j] * sc + b, 0.f);
    }
  }
}

// Per-pixel scaled-dot attention over cav axis (n=3), keep ego row.
// in: (3, C, HW), out: (C, HW)
__global__ __launch_bounds__(256) void fuse_k(const float* __restrict__ in,
                                              float* __restrict__ out,
                                              int C, int HW, float inv_sqrtC) {
  const int p = blockIdx.x * 256 + threadIdx.x;
  const float* v0 = in + p;
  const float* v1 = in + (size_t)C * HW + p;
  const float* v2 = in + 2 * (size_t)C * HW + p;
  float d00 = 0.f, d01 = 0.f, d02 = 0.f;
  for (int c = 0; c < C; ++c) {
    const size_t o = (size_t)c * HW;
    float a = v0[o], b = v1[o], d = v2[o];
    d00 += a * a; d01 += a * b; d02 += a * d;
  }
  float s0 = d00 * inv_sqrtC, s1 = d01 * inv_sqrtC, s2 = d02 * inv_sqrtC;
  float m = fmaxf(s0, fmaxf(s1, s2));
  float e0 = expf(s0 - m), e1 = expf(s1 - m), e2 = expf(s2 - m);
  float inv = 1.0f / (e0 + e1 + e2);
  float a0 = e0 * inv, a1 = e1 * inv, a2 = e2 * inv;
  for (int c = 0; c < C; ++c) {
    const size_t o = (size_t)c * HW;
    out[o + p] = a0 * v0[o] + a1 * v1[o] + a2 * v2[o];
  }
}

// 1x1 conv: f (64, 32768) -> out (128, 32768). Block: 16 o, thread: 4 o x 4 px.
__global__ __launch_bounds__(256) void up0_k(const float* __restrict__ f,
                                             const float* __restrict__ wgt,
                                             const float* __restrict__ bias,
                                             float* __restrict__ out) {
  const int tid = threadIdx.x, lane = tid & 63, og = tid >> 6;
  const int o0 = blockIdx.y * 16;
  const int p0 = blockIdx.x * 256 + lane;
  __shared__ float wl[64 * 16];  // [i][o_sub]
  for (int idx = tid; idx < 1024; idx += 256) {
    int os = idx >> 6, i = idx & 63;
    wl[i * 16 + os] = wgt[(size_t)(o0 + os) * 64 + i];
  }
  __syncthreads();
  float acc[4][4];
#pragma unroll
  for (int k = 0; k < 4; ++k)
#pragma unroll
    for (int j = 0; j < 4; ++j) acc[k][j] = 0.f;
  for (int i = 0; i < 64; ++i) {
    const float* fp = f + (size_t)i * HW0 + p0;
    float4 w4 = *(const float4*)&wl[i * 16 + og * 4];
    float fv[4];
#pragma unroll
    for (int k = 0; k < 4; ++k) fv[k] = fp[k * 64];
#pragma unroll
    for (int k = 0; k < 4; ++k) {
      acc[k][0] += fv[k] * w4.x; acc[k][1] += fv[k] * w4.y;
      acc[k][2] += fv[k] * w4.z; acc[k][3] += fv[k] * w4.w;
    }
  }
#pragma unroll
  for (int j = 0; j < 4; ++j) {
    const int o = o0 + og * 4 + j;
    const float b = bias[o];
    float* op = out + (size_t)o * HW0 + p0;
#pragma unroll
    for (int k = 0; k < 4; ++k) op[k * 64] = acc[k][j] + b;
  }
}

// 2x deconv (k=s=2, VALID): out[o, 2h+r, 2w+c] = b + sum_i f[i,h,w]*W[o,i,1-r,1-c]
// f: (128,64,128), wgt: (128,128,2,2), out region: (128,128,256)
__global__ __launch_bounds__(256) void up1_k(const float* __restrict__ f,
                                             const float* __restrict__ wgt,
                                             const float* __restrict__ bias,
                                             float* __restrict__ out) {
  const int tid = threadIdx.x, lane = tid & 63, og = tid >> 6;
  const int o0 = blockIdx.y * 8;
  const int h = blockIdx.x;        // input row 0..63
  const int c = lane & 1;
  const int wbase = lane >> 1;     // + 32*k
  __shared__ float wl[128 * 4 * 8];  // [i][rc][o_sub]
  for (int idx = tid; idx < 128 * 4 * 8; idx += 256) {
    int os = idx >> 9;
    int rem = idx & 511;
    int i = rem >> 2, rc = rem & 3;
    wl[(i * 4 + rc) * 8 + os] = wgt[((size_t)(o0 + os) * 128 + i) * 4 + rc];
  }
  __syncthreads();
  float acc[2][2][4];  // [j][r][k]
#pragma unroll
  for (int j = 0; j < 2; ++j)
#pragma unroll
    for (int r = 0; r < 2; ++r)
#pragma unroll
      for (int k = 0; k < 4; ++k) acc[j][r][k] = 0.f;
  const int rc_r0 = 2 + (1 - c);   // (1-0)*2 + (1-c)
  const int rc_r1 = (1 - c);       // (1-1)*2 + (1-c)
  for (int i = 0; i < 128; ++i) {
    const float* frow = f + ((size_t)i * 64 + h) * 128;
    float fv[4];
#pragma unroll
    for (int k = 0; k < 4; ++k) fv[k] = frow[wbase + 32 * k];
    float2 w0 = *(const float2*)&wl[(i * 4 + rc_r0) * 8 + og * 2];
    float2 w1 = *(const float2*)&wl[(i * 4 + rc_r1) * 8 + og * 2];
#pragma unroll
    for (int k = 0; k < 4; ++k) {
      acc[0][0][k] += fv[k] * w0.x; acc[1][0][k] += fv[k] * w0.y;
      acc[0][1][k] += fv[k] * w1.x; acc[1][1][k] += fv[k] * w1.y;
    }
  }
#pragma unroll
  for (int j = 0; j < 2; ++j) {
    const int o = o0 + og * 2 + j;
    const float b = bias[o];
#pragma unroll
    for (int r = 0; r < 2; ++r) {
      float* op = out + (size_t)o * HW0 + (size_t)(2 * h + r) * 256 + lane;
#pragma unroll
      for (int k = 0; k < 4; ++k) op[64 * k] = acc[j][r][k] + b;
    }
  }
}

// 4x deconv (k=s=4): out[o, 4h+r, 4w+c] = b + sum_i f[i,h,w]*W[o,i,3-r,3-c]
// f: (256,32,64), wgt: (128,256,4,4), out region: (128,128,256)
__global__ __launch_bounds__(256) void up2_k(const float* __restrict__ f,
                                             const float* __restrict__ wgt,
                                             const float* __restrict__ bias,
                                             float* __restrict__ out) {
  const int tid = threadIdx.x, lane = tid & 63, og = tid >> 6;
  const int o0 = blockIdx.y * 4;
  const int h = blockIdx.x;        // input row 0..31
  const int c = lane & 3;
  const int wbase = lane >> 2;     // + 16*k
  __shared__ float wl[256 * 16 * 4];  // [i][rc][o_sub], 64 KB
  for (int idx = tid; idx < 256 * 16 * 4; idx += 256) {
    int os = idx >> 12;
    int rem = idx & 4095;
    int i = rem >> 4, rc = rem & 15;
    wl[(i * 16 + rc) * 4 + os] = wgt[((size_t)(o0 + os) * 256 + i) * 16 + rc];
  }
  __syncthreads();
  float acc[4][4];  // [r][k]
#pragma unroll
  for (int r = 0; r < 4; ++r)
#pragma unroll
    for (int k = 0; k < 4; ++k) acc[r][k] = 0.f;
  for (int i = 0; i < 256; ++i) {
    const float* frow = f + ((size_t)i * 32 + h) * 64;
    float fv[4];
#pragma unroll
    for (int k = 0; k < 4; ++k) fv[k] = frow[wbase + 16 * k];
    float wv[4];
#pragma unroll
    for (int r = 0; r < 4; ++r) wv[r] = wl[(i * 16 + (3 - r) * 4 + (3 - c)) * 4 + og];
#pragma unroll
    for (int r = 0; r < 4; ++r)
#pragma unroll
      for (int k = 0; k < 4; ++k) acc[r][k] += fv[k] * wv[r];
  }
  const int o = o0 + og;
  const float b = bias[o];
#pragma unroll
  for (int r = 0; r < 4; ++r) {
    float* op = out + (size_t)o * HW0 + (size_t)(4 * h + r) * 256 + lane;
#pragma unroll
    for (int k = 0; k < 4; ++k) op[64 * k] = acc[r][k] + b;
  }
}

// per-channel mean & max over 32768 pixels of x_fuse
__global__ __launch_bounds__(256) void sta_reduce_k(const float* __restrict__ xf,
                                                    float* __restrict__ mean,
                                                    float* __restrict__ mx) {
  const int c = blockIdx.x;
  const float* p = xf + (size_t)c * HW0;
  float s = 0.f, m = -1e30f;
  for (int i = threadIdx.x * 4; i < HW0; i += 1024) {
    float4 v = *(const float4*)(p + i);
    s += v.x + v.y + v.z + v.w;
    m = fmaxf(m, fmaxf(fmaxf(v.x, v.y), fmaxf(v.z, v.w)));
  }
#pragma unroll
  for (int off = 32; off; off >>= 1) {
    s += __shfl_down(s, off);
    m = fmaxf(m, __shfl_down(m, off));
  }
  __shared__ float ss[4], sm[4];
  if ((threadIdx.x & 63) == 0) { ss[threadIdx.x >> 6] = s; sm[threadIdx.x >> 6] = m; }
  __syncthreads();
  if (threadIdx.x == 0) {
    float S = ss[0] + ss[1] + ss[2] + ss[3];
    float M = fmaxf(fmaxf(sm[0], sm[1]), fmaxf(sm[2], sm[3]));
    mean[c] = S * (1.0f / 32768.0f);
    mx[c] = M;
  }
}

// gate = sigmoid(relu(avg@w1^T)@w2^T + relu(max@w1^T)@w2^T)
__global__ void sta_gate_k(const float* __restrict__ mean, const float* __restrict__ mx,
                           const float* __restrict__ w1, const float* __restrict__ w2,
                           float* __restrict__ gate) {
  __shared__ float havg[32], hmax[32];
  const int t = threadIdx.x;
  if (t < 32) {
    float sa = 0.f, sm = 0.f;
    for (int cc = 0; cc < 512; ++cc) {
      float w = w1[t * 512 + cc];
      sa += mean[cc] * w;
      sm += mx[cc] * w;
    }
    havg[t] = fmaxf(sa, 0.f);
    hmax[t] = fmaxf(sm, 0.f);
  }
  __syncthreads();
  float g = 0.f;
  for (int j = 0; j < 32; ++j) g += (havg[j] + hmax[j]) * w2[t * 32 + j];
  gate[t] = 1.0f / (1.0f + expf(-g));
}

__global__ __launch_bounds__(256) void sta_scale_k(float* __restrict__ xf,
                                                   const float* __restrict__ gate) {
  const size_t i = (size_t)(blockIdx.x * 256 + threadIdx.x) * 4;
  float4 v = *(const float4*)(xf + i);
  const float g = gate[i >> 15];
  v.x *= g; v.y *= g; v.z *= g; v.w *= g;
  *(float4*)(xf + i) = v;
}

extern "C" void kernel_launch(void* const* d_in, const int* in_sizes, int n_in,
                              void* d_out, int out_size, void* d_ws, size_t ws_size,
                              hipStream_t stream) {
  const float* x    = (const float*)d_in[0];   // (3,64,256,512)
  const float* hist = (const float*)d_in[1];   // (2,64,256,512)
  const float* td   = (const float*)d_in[4];   // (1,5)
  const float* ew   = (const float*)d_in[6];
  const float* eb   = (const float*)d_in[7];
  const float* b0w  = (const float*)d_in[8];
  const float* b0b  = (const float*)d_in[9];
  const float* b1w  = (const float*)d_in[10];
  const float* b1b  = (const float*)d_in[11];
  const float* b2w  = (const float*)d_in[12];
  const float* b2b  = (const float*)d_in[13];
  const float* d0w  = (const float*)d_in[14];
  const float* d0b  = (const float*)d_in[15];
  const float* d1w  = (const float*)d_in[16];
  const float* d1b  = (const float*)d_in[17];
  const float* d2w  = (const float*)d_in[18];
  const float* d2b  = (const float*)d_in[19];
  const float* w1   = (const float*)d_in[20];
  const float* w2   = (const float*)d_in[21];

  float* out = (float*)d_out;  // (512,128,256)
  float* ws  = (float*)d_ws;

  float* scales = ws + WS_SCALES;
  float* l0x = ws + WS_L0X;
  float* l1  = ws + WS_L1;
  float* l2  = ws + WS_L2;
  float* f0  = ws + WS_F0;
  float* f1  = ws + WS_F1;
  float* f2  = ws + WS_F2;

  prep_k<<<1, 64, 0, stream>>>(td, ew, eb, scales);

  // level-0 conv on x (3 imgs) and historical (2 imgs)
  conv3x3s2_k<64, 4, 0><<<dim3(2, 128, 12), 256, 0, stream>>>(
      x, b0w, b0b, l0x, scales, 64, 256, 512);
  conv3x3s2_k<64, 4, 0><<<dim3(2, 128, 8), 256, 0, stream>>>(
      hist, b0w, b0b, out + (size_t)384 * HW0, scales + 3, 64, 256, 512);

  fuse_k<<<128, 256, 0, stream>>>(l0x, f0, 64, 32768, 0.125f);
  up0_k<<<dim3(128, 8), 256, 0, stream>>>(f0, d0w, d0b, out);

  conv3x3s2_k<64, 4, 0><<<dim3(1, 64, 24), 256, 0, stream>>>(
      l0x, b1w, b1b, l1, nullptr, 128, 128, 256);
  fuse_k<<<32, 256, 0, stream>>>(l1, f1, 128, 8192, 0.0883883476f);
  up1_k<<<dim3(64, 16), 256, 0, stream>>>(f1, d1w, d1b, out + (size_t)128 * HW0);

  conv3x3s2_k<128, 2, 1><<<dim3(1, 16, 96), 256, 0, stream>>>(
      l1, b2w, b2b, l2, nullptr, 256, 64, 128);
  fuse_k<<<8, 256, 0, stream>>>(l2, f2, 256, 2048, 0.0625f);
  up2_k<<<dim3(32, 32), 256, 0, stream>>>(f2, d2w, d2b, out + (size_t)256 * HW0);

  sta_reduce_k<<<512, 256, 0, stream>>>(out, ws + WS_MEAN, ws + WS_MAX);
  sta_gate_k<<<1, 512, 0, stream>>>(ws + WS_MEAN, ws + WS_MAX, w1, w2, ws + WS_GATE);
  sta_scale_k<<<16384, 256, 0, stream>>>(out, ws + WS_GATE);
}

// Round 4
// 756.317 us; speedup vs baseline: 2.4260x; 2.4260x over previous
//
#include <hip/hip_runtime.h>
#include <math.h>

#define HW0 32768  // 128*256 output plane

typedef __attribute__((ext_vector_type(8))) short short8v;
typedef __attribute__((ext_vector_type(4))) float f32x4;

// workspace layout (floats)
static const size_t WS_SCALES = 0;                                   // 5
static const size_t WS_MEAN   = 64;                                  // 512
static const size_t WS_MAX    = 64 + 512;                            // 512
static const size_t WS_GATE   = 64 + 1024;                           // 512
static const size_t WS_L0X    = 2048;                                // 3*64*128*256   = 6291456
static const size_t WS_L1     = WS_L0X + (size_t)3*64*128*256;       // 3*128*64*128  = 3145728
static const size_t WS_L2     = WS_L1  + (size_t)3*128*64*128;       // 3*256*32*64   = 1572864
static const size_t WS_F0     = WS_L2  + (size_t)3*256*32*64;        // 64*128*256    = 2097152
static const size_t WS_F1     = WS_F0  + (size_t)64*128*256;         // 128*64*128    = 1048576
static const size_t WS_F2     = WS_F1  + (size_t)128*64*128;         // 256*32*64     = 524288
static const size_t WS_W0P    = WS_F2  + (size_t)256*32*64;          // 64*576  bf16 -> 18432 floats
static const size_t WS_W1P    = WS_W0P + 18432;                      // 128*576 bf16 -> 36864 floats
static const size_t WS_W2P    = WS_W1P + 36864;                      // 256*1152 bf16 -> 147456 floats
static const size_t WS_STG    = WS_W2P + 147456;                     // shared NHWC bf16 staging:
// max(xh 3*256*512*64, hh 2*..., l0h 3*128*256*64, l1h 3*64*128*128) = 25165824 shorts = 12582912 floats
// reused SERIALLY: xh -> (conv0x) -> hh -> (convh) -> l0h -> (conv1) -> l1h -> (conv2)

__device__ inline unsigned short f2bf(float x) {
  unsigned u = __float_as_uint(x);
  unsigned r = ((u >> 16) & 1u) + 0x7FFFu;
  return (unsigned short)((u + r) >> 16);
}

__global__ void prep_k(const float* __restrict__ td, const float* __restrict__ ew,
                       const float* __restrict__ eb, float* __restrict__ scales) {
  int i = threadIdx.x;
  if (i < 5) {
    float e = tanhf(ew[0] * (1.0f / (td[i] + 0.1f)) + eb[0]) + 1.0f;
    // images fed to conv0: [x0, x1, x2, h0, h1] get [enw0, enw3, enw4, enw1, enw2]
    const int slot[5] = {0, 3, 4, 1, 2};
    scales[slot[i]] = e;
  }
}

// NCHW f32 -> NHWC bf16 (per 64-channel block), LDS tile transpose.
// grid: (W/64, H, N*C/64), block 256.
__global__ __launch_bounds__(256) void repack_k(const float* __restrict__ in,
                                                unsigned short* __restrict__ outh,
                                                int C, int H, int W) {
  __shared__ unsigned short lds[64 * 72];
  const int t = threadIdx.x;
  const int cbn = C >> 6;
  const int n  = blockIdx.z / cbn;
  const int cb = (blockIdx.z % cbn) << 6;
  const int h  = blockIdx.y;
  const int w0 = blockIdx.x << 6;
  const int wl = t & 63, cg = t >> 6;
  const float* ip = in + (((size_t)n * C + cb) * H + h) * W + w0;
#pragma unroll 4
  for (int cj = 0; cj < 16; ++cj) {
    int c = cg * 16 + cj;
    lds[wl * 72 + c] = f2bf(ip[(size_t)c * H * W + wl]);
  }
  __syncthreads();
  const int pw = t >> 2, ch = t & 3;
  unsigned short* op = outh + ((size_t)n * H * W + (size_t)h * W + w0 + pw) * C + cb;
#pragma unroll
  for (int it = 0; it < 2; ++it) {
    int c0 = (ch + it * 4) * 8;
    *(uint4*)(op + c0) = *(const uint4*)(lds + pw * 72 + c0);
  }
}

// Pack conv weights (Cout,Cin,3,3) f32 -> bf16 fragment order [cog][kstep][lane][8],
// k-order = tap*Cin + ci (tap = ky*3+kx). One thread per (co, kstep, js) octet.
__global__ void pack_w_k(const float* __restrict__ W, unsigned short* __restrict__ wp,
                         int Cout, int Cin, int NK) {
  int t = blockIdx.x * 256 + threadIdx.x;
  if (t >= Cout * NK * 4) return;
  int co = t / (NK * 4); int rem = t - co * (NK * 4); int s = rem >> 2; int js = rem & 3;
  int cog = co >> 4; int l = js * 16 + (co & 15);
  unsigned short v[8];
#pragma unroll
  for (int j = 0; j < 8; ++j) {
    int k = s * 32 + js * 8 + j;
    int tap = k / Cin, ci = k - tap * Cin;
    int ky = tap / 3, kx = tap - ky * 3;
    v[j] = f2bf(W[(((size_t)co * Cin + ci) * 3 + ky) * 3 + kx]);
  }
  *(uint4*)(wp + ((size_t)(cog * NK + s) * 64 + l) * 8) = *(uint4*)v;
}

// 3x3 stride-2 pad-1 conv + scale + bias + relu via MFMA implicit GEMM.
// Input NHWC bf16, output NCHW f32. Block: 4 waves x 16px = 64 px of one output
// row, COG*16 out-channels. grid: (Wout/64, Hout, N*cogrp).
// D = A(weights 16co x 32k) * B(patches 32k x 16px); per k-step: 1 global B-load
// (16B/lane, contiguous ci in NHWC), COG ds_read_b128 A, COG MFMA.
template <int CIN, int COG>
__global__ __launch_bounds__(256) void conv_mfma_k(
    const unsigned short* __restrict__ inh, const unsigned short* __restrict__ wp,
    const float* __restrict__ bias, float* __restrict__ out,
    const float* __restrict__ scales, int Cout, int Hout, int Wout, int cogrp) {
  constexpr int NK = (9 * CIN) / 32;
  extern __shared__ unsigned short wlds[];
  const int tid = threadIdx.x, lane = tid & 63, wv = tid >> 6;
  const int Hin = Hout * 2, Win = Wout * 2;
  const int n   = blockIdx.z / cogrp;
  const int cg  = blockIdx.z % cogrp;
  const int co0 = cg * (COG * 16);
  const int h   = blockIdx.y;
  const int w0  = blockIdx.x * 64;

  {  // stage this block's packed weights (contiguous, conflict-free)
    const float4* src = (const float4*)(wp + (size_t)(co0 >> 4) * NK * 64 * 8);
    float4* dst = (float4*)wlds;
    for (int i = tid; i < COG * NK * 64; i += 256) dst[i] = src[i];
  }
  __syncthreads();

  const int px = w0 + wv * 16 + (lane & 15);  // this lane's output pixel (n-index)
  const int js = lane >> 4;                   // k-slice group
  const unsigned short* inp = inh + (size_t)n * CIN * Hin * Win;

  f32x4 acc[COG];
#pragma unroll
  for (int c = 0; c < COG; ++c) acc[c] = (f32x4){0.f, 0.f, 0.f, 0.f};

  const short8v bz = {0, 0, 0, 0, 0, 0, 0, 0};
  for (int s = 0; s < NK; ++s) {
    const int tap = (s * 32) / CIN;            // 32-slice never crosses a tap
    const int ci  = (s * 32) % CIN + js * 8;
    const int ky = tap / 3, kx = tap - ky * 3;
    const int iy = 2 * h + ky - 1;             // block-uniform
    short8v b = bz;
    if (iy >= 0) {                             // pad: only iy<0 / ix<0 can be OOB
      const int ix = 2 * px + kx - 1;
      const unsigned short* p = inp + ((size_t)iy * Win + (ix < 0 ? 0 : ix)) * CIN + ci;
      short8v v = *(const short8v*)p;
      if (ix >= 0) b = v;                      // per-lane zero for left edge
    }
#pragma unroll
    for (int c = 0; c < COG; ++c) {
      short8v a = *(const short8v*)&wlds[((c * NK + s) * 64 + lane) * 8];
      acc[c] = __builtin_amdgcn_mfma_f32_16x16x32_bf16(a, b, acc[c], 0, 0, 0);
    }
  }

  const float sc = scales ? scales[n] : 1.0f;
#pragma unroll
  for (int c = 0; c < COG; ++c) {
#pragma unroll
    for (int r = 0; r < 4; ++r) {
      const int co = co0 + c * 16 + js * 4 + r;  // D row = 4*(lane>>4)+reg
      float v = fmaxf(acc[c][r] * sc + bias[co], 0.f);
      out[(((size_t)n * Cout + co) * Hout + h) * Wout + px] = v;
    }
  }
}

// Per-pixel scaled-dot attention over cav axis (n=3), keep ego row.
__global__ __launch_bounds__(256) void fuse_k(const float* __restrict__ in,
                                              float* __restrict__ out,
                                              int C, int HW, float inv_sqrtC) {
  const int p = blockIdx.x * 256 + threadIdx.x;
  const float* v0 = in + p;
  const float* v1 = in + (size_t)C * HW + p;
  const float* v2 = in + 2 * (size_t)C * HW + p;
  float d00 = 0.f, d01 = 0.f, d02 = 0.f;
  for (int c = 0; c < C; ++c) {
    const size_t o = (size_t)c * HW;
    float a = v0[o], b = v1[o], d = v2[o];
    d00 += a * a; d01 += a * b; d02 += a * d;
  }
  float s0 = d00 * inv_sqrtC, s1 = d01 * inv_sqrtC, s2 = d02 * inv_sqrtC;
  float m = fmaxf(s0, fmaxf(s1, s2));
  float e0 = expf(s0 - m), e1 = expf(s1 - m), e2 = expf(s2 - m);
  float inv = 1.0f / (e0 + e1 + e2);
  float a0 = e0 * inv, a1 = e1 * inv, a2 = e2 * inv;
  for (int c = 0; c < C; ++c) {
    const size_t o = (size_t)c * HW;
    out[o + p] = a0 * v0[o] + a1 * v1[o] + a2 * v2[o];
  }
}

// 1x1 conv: f (64, 32768) -> out (128, 32768).
__global__ __launch_bounds__(256) void up0_k(const float* __restrict__ f,
                                             const float* __restrict__ wgt,
                                             const float* __restrict__ bias,
                                             float* __restrict__ out) {
  const int tid = threadIdx.x, lane = tid & 63, og = tid >> 6;
  const int o0 = blockIdx.y * 16;
  const int p0 = blockIdx.x * 256 + lane;
  __shared__ float wl[64 * 16];
  for (int idx = tid; idx < 1024; idx += 256) {
    int os = idx >> 6, i = idx & 63;
    wl[i * 16 + os] = wgt[(size_t)(o0 + os) * 64 + i];
  }
  __syncthreads();
  float acc[4][4];
#pragma unroll
  for (int k = 0; k < 4; ++k)
#pragma unroll
    for (int j = 0; j < 4; ++j) acc[k][j] = 0.f;
  for (int i = 0; i < 64; ++i) {
    const float* fp = f + (size_t)i * HW0 + p0;
    float4 w4 = *(const float4*)&wl[i * 16 + og * 4];
    float fv[4];
#pragma unroll
    for (int k = 0; k < 4; ++k) fv[k] = fp[k * 64];
#pragma unroll
    for (int k = 0; k < 4; ++k) {
      acc[k][0] += fv[k] * w4.x; acc[k][1] += fv[k] * w4.y;
      acc[k][2] += fv[k] * w4.z; acc[k][3] += fv[k] * w4.w;
    }
  }
#pragma unroll
  for (int j = 0; j < 4; ++j) {
    const int o = o0 + og * 4 + j;
    const float b = bias[o];
    float* op = out + (size_t)o * HW0 + p0;
#pragma unroll
    for (int k = 0; k < 4; ++k) op[k * 64] = acc[k][j] + b;
  }
}

// 2x deconv (k=s=2): out[o,2h+r,2w+c] = b + sum_i f[i,h,w]*W[o,i,1-r,1-c]
__global__ __launch_bounds__(256) void up1_k(const float* __restrict__ f,
                                             const float* __restrict__ wgt,
                                             const float* __restrict__ bias,
                                             float* __restrict__ out) {
  const int tid = threadIdx.x, lane = tid & 63, og = tid >> 6;
  const int o0 = blockIdx.y * 8;
  const int h = blockIdx.x;
  const int c = lane & 1;
  const int wbase = lane >> 1;
  __shared__ float wl[128 * 4 * 8];
  for (int idx = tid; idx < 128 * 4 * 8; idx += 256) {
    int os = idx >> 9;
    int rem = idx & 511;
    int i = rem >> 2, rc = rem & 3;
    wl[(i * 4 + rc) * 8 + os] = wgt[((size_t)(o0 + os) * 128 + i) * 4 + rc];
  }
  __syncthreads();
  float acc[2][2][4];
#pragma unroll
  for (int j = 0; j < 2; ++j)
#pragma unroll
    for (int r = 0; r < 2; ++r)
#pragma unroll
      for (int k = 0; k < 4; ++k) acc[j][r][k] = 0.f;
  const int rc_r0 = 2 + (1 - c);
  const int rc_r1 = (1 - c);
  for (int i = 0; i < 128; ++i) {
    const float* frow = f + ((size_t)i * 64 + h) * 128;
    float fv[4];
#pragma unroll
    for (int k = 0; k < 4; ++k) fv[k] = frow[wbase + 32 * k];
    float2 w0 = *(const float2*)&wl[(i * 4 + rc_r0) * 8 + og * 2];
    float2 w1 = *(const float2*)&wl[(i * 4 + rc_r1) * 8 + og * 2];
#pragma unroll
    for (int k = 0; k < 4; ++k) {
      acc[0][0][k] += fv[k] * w0.x; acc[1][0][k] += fv[k] * w0.y;
      acc[0][1][k] += fv[k] * w1.x; acc[1][1][k] += fv[k] * w1.y;
    }
  }
#pragma unroll
  for (int j = 0; j < 2; ++j) {
    const int o = o0 + og * 2 + j;
    const float b = bias[o];
#pragma unroll
    for (int r = 0; r < 2; ++r) {
      float* op = out + (size_t)o * HW0 + (size_t)(2 * h + r) * 256 + lane;
#pragma unroll
      for (int k = 0; k < 4; ++k) op[64 * k] = acc[j][r][k] + b;
    }
  }
}

// 4x deconv (k=s=4): out[o,4h+r,4w+c] = b + sum_i f[i,h,w]*W[o,i,3-r,3-c]
__global__ __launch_bounds__(256) void up2_k(const float* __restrict__ f,
                                             const float* __restrict__ wgt,
                                             const float* __restrict__ bias,
                                             float* __restrict__ out) {
  const int tid = threadIdx.x, lane = tid & 63, og = tid >> 6;
  const int o0 = blockIdx.y * 4;
  const int h = blockIdx.x;
  const int c = lane & 3;
  const int wbase = lane >> 2;
  __shared__ float wl[256 * 16 * 4];
  for (int idx = tid; idx < 256 * 16 * 4; idx += 256) {
    int os = idx >> 12;
    int rem = idx & 4095;
    int i = rem >> 4, rc = rem & 15;
    wl[(i * 16 + rc) * 4 + os] = wgt[((size_t)(o0 + os) * 256 + i) * 16 + rc];
  }
  __syncthreads();
  float acc[4][4];
#pragma unroll
  for (int r = 0; r < 4; ++r)
#pragma unroll
    for (int k = 0; k < 4; ++k) acc[r][k] = 0.f;
  for (int i = 0; i < 256; ++i) {
    const float* frow = f + ((size_t)i * 32 + h) * 64;
    float fv[4];
#pragma unroll
    for (int k = 0; k < 4; ++k) fv[k] = frow[wbase + 16 * k];
    float wv[4];
#pragma unroll
    for (int r = 0; r < 4; ++r) wv[r] = wl[(i * 16 + (3 - r) * 4 + (3 - c)) * 4 + og];
#pragma unroll
    for (int r = 0; r < 4; ++r)
#pragma unroll
      for (int k = 0; k < 4; ++k) acc[r][k] += fv[k] * wv[r];
  }
  const int o = o0 + og;
  const float b = bias[o];
#pragma unroll
  for (int r = 0; r < 4; ++r) {
    float* op = out + (size_t)o * HW0 + (size_t)(4 * h + r) * 256 + lane;
#pragma unroll
    for (int k = 0; k < 4; ++k) op[64 * k] = acc[r][k] + b;
  }
}

// per-channel mean & max over 32768 pixels of x_fuse
__global__ __launch_bounds__(256) void sta_reduce_k(const float* __restrict__ xf,
                                                    float* __restrict__ mean,
                                                    float* __restrict__ mx) {
  const int c = blockIdx.x;
  const float* p = xf + (size_t)c * HW0;
  float s = 0.f, m = -1e30f;
  for (int i = threadIdx.x * 4; i < HW0; i += 1024) {
    float4 v = *(const float4*)(p + i);
    s += v.x + v.y + v.z + v.w;
    m = fmaxf(m, fmaxf(fmaxf(v.x, v.y), fmaxf(v.z, v.w)));
  }
#pragma unroll
  for (int off = 32; off; off >>= 1) {
    s += __shfl_down(s, off);
    m = fmaxf(m, __shfl_down(m, off));
  }
  __shared__ float ss[4], sm[4];
  if ((threadIdx.x & 63) == 0) { ss[threadIdx.x >> 6] = s; sm[threadIdx.x >> 6] = m; }
  __syncthreads();
  if (threadIdx.x == 0) {
    float S = ss[0] + ss[1] + ss[2] + ss[3];
    float M = fmaxf(fmaxf(sm[0], sm[1]), fmaxf(sm[2], sm[3]));
    mean[c] = S * (1.0f / 32768.0f);
    mx[c] = M;
  }
}

__global__ void sta_gate_k(const float* __restrict__ mean, const float* __restrict__ mx,
                           const float* __restrict__ w1, const float* __restrict__ w2,
                           float* __restrict__ gate) {
  __shared__ float havg[32], hmax[32];
  const int t = threadIdx.x;
  if (t < 32) {
    float sa = 0.f, sm = 0.f;
    for (int cc = 0; cc < 512; ++cc) {
      float w = w1[t * 512 + cc];
      sa += mean[cc] * w;
      sm += mx[cc] * w;
    }
    havg[t] = fmaxf(sa, 0.f);
    hmax[t] = fmaxf(sm, 0.f);
  }
  __syncthreads();
  float g = 0.f;
  for (int j = 0; j < 32; ++j) g += (havg[j] + hmax[j]) * w2[t * 32 + j];
  gate[t] = 1.0f / (1.0f + expf(-g));
}

__global__ __launch_bounds__(256) void sta_scale_k(float* __restrict__ xf,
                                                   const float* __restrict__ gate) {
  const size_t i = (size_t)(blockIdx.x * 256 + threadIdx.x) * 4;
  float4 v = *(const float4*)(xf + i);
  const float g = gate[i >> 15];
  v.x *= g; v.y *= g; v.z *= g; v.w *= g;
  *(float4*)(xf + i) = v;
}

extern "C" void kernel_launch(void* const* d_in, const int* in_sizes, int n_in,
                              void* d_out, int out_size, void* d_ws, size_t ws_size,
                              hipStream_t stream) {
  const float* x    = (const float*)d_in[0];   // (3,64,256,512)
  const float* hist = (const float*)d_in[1];   // (2,64,256,512)
  const float* td   = (const float*)d_in[4];   // (1,5)
  const float* ew   = (const float*)d_in[6];
  const float* eb   = (const float*)d_in[7];
  const float* b0w  = (const float*)d_in[8];
  const float* b0b  = (const float*)d_in[9];
  const float* b1w  = (const float*)d_in[10];
  const float* b1b  = (const float*)d_in[11];
  const float* b2w  = (const float*)d_in[12];
  const float* b2b  = (const float*)d_in[13];
  const float* d0w  = (const float*)d_in[14];
  const float* d0b  = (const float*)d_in[15];
  const float* d1w  = (const float*)d_in[16];
  const float* d1b  = (const float*)d_in[17];
  const float* d2w  = (const float*)d_in[18];
  const float* d2b  = (const float*)d_in[19];
  const float* w1   = (const float*)d_in[20];
  const float* w2   = (const float*)d_in[21];

  float* out = (float*)d_out;  // (512,128,256)
  float* ws  = (float*)d_ws;

  float* scales = ws + WS_SCALES;
  float* l0x = ws + WS_L0X;
  float* l1  = ws + WS_L1;
  float* l2  = ws + WS_L2;
  float* f0  = ws + WS_F0;
  float* f1  = ws + WS_F1;
  float* f2  = ws + WS_F2;
  unsigned short* w0p = (unsigned short*)(ws + WS_W0P);
  unsigned short* w1p = (unsigned short*)(ws + WS_W1P);
  unsigned short* w2p = (unsigned short*)(ws + WS_W2P);
  unsigned short* stg = (unsigned short*)(ws + WS_STG);  // serially reused NHWC bf16

  prep_k<<<1, 64, 0, stream>>>(td, ew, eb, scales);
  pack_w_k<<<18, 256, 0, stream>>>(b0w, w0p, 64, 64, 18);
  pack_w_k<<<36, 256, 0, stream>>>(b1w, w1p, 128, 64, 18);
  pack_w_k<<<144, 256, 0, stream>>>(b2w, w2p, 256, 128, 36);

  // ---- level 0 on x: repack -> MFMA conv (scale folded into epilogue)
  repack_k<<<dim3(8, 256, 3), 256, 0, stream>>>(x, stg, 64, 256, 512);
  conv_mfma_k<64, 4><<<dim3(4, 128, 3), 256, 73728, stream>>>(
      stg, w0p, b0b, l0x, scales, 64, 128, 256, 1);

  // ---- level 0 on historical (stg reused; prior reads complete, stream-serial)
  repack_k<<<dim3(8, 256, 2), 256, 0, stream>>>(hist, stg, 64, 256, 512);
  conv_mfma_k<64, 4><<<dim3(4, 128, 2), 256, 73728, stream>>>(
      stg, w0p, b0b, out + (size_t)384 * HW0, scales + 3, 64, 128, 256, 1);

  fuse_k<<<128, 256, 0, stream>>>(l0x, f0, 64, 32768, 0.125f);
  up0_k<<<dim3(128, 8), 256, 0, stream>>>(f0, d0w, d0b, out);

  // ---- level 1
  repack_k<<<dim3(4, 128, 3), 256, 0, stream>>>(l0x, stg, 64, 128, 256);
  conv_mfma_k<64, 4><<<dim3(2, 64, 6), 256, 73728, stream>>>(
      stg, w1p, b1b, l1, nullptr, 128, 64, 128, 2);
  fuse_k<<<32, 256, 0, stream>>>(l1, f1, 128, 8192, 0.0883883476f);
  up1_k<<<dim3(64, 16), 256, 0, stream>>>(f1, d1w, d1b, out + (size_t)128 * HW0);

  // ---- level 2
  repack_k<<<dim3(2, 64, 6), 256, 0, stream>>>(l1, stg, 128, 64, 128);
  conv_mfma_k<128, 2><<<dim3(1, 32, 24), 256, 73728, stream>>>(
      stg, w2p, b2b, l2, nullptr, 256, 32, 64, 8);
  fuse_k<<<8, 256, 0, stream>>>(l2, f2, 256, 2048, 0.0625f);
  up2_k<<<dim3(32, 32), 256, 0, stream>>>(f2, d2w, d2b, out + (size_t)256 * HW0);

  // ---- STA gate
  sta_reduce_k<<<512, 256, 0, stream>>>(out, ws + WS_MEAN, ws + WS_MAX);
  sta_gate_k<<<1, 512, 0, stream>>>(ws + WS_MEAN, ws + WS_MAX, w1, w2, ws + WS_GATE);
  sta_scale_k<<<16384, 256, 0, stream>>>(out, ws + WS_GATE);
}

// Round 6
// 585.950 us; speedup vs baseline: 3.1314x; 1.2908x over previous
//
#include <hip/hip_runtime.h>
#include <math.h>

#define HW0 32768  // 128*256 output plane

typedef __attribute__((ext_vector_type(8))) short short8v;
typedef __attribute__((ext_vector_type(4))) float f32x4;

// workspace layout (floats)
static const size_t WS_SCALES = 0;                                   // 5
static const size_t WS_MEAN   = 64;                                  // 512
static const size_t WS_MAX    = 64 + 512;                            // 512
static const size_t WS_GATE   = 64 + 1024;                           // 512
static const size_t WS_L0X    = 2048;                                // 3*64*128*256   = 6291456
static const size_t WS_L1     = WS_L0X + (size_t)3*64*128*256;       // 3*128*64*128  = 3145728
static const size_t WS_L2     = WS_L1  + (size_t)3*128*64*128;       // 3*256*32*64   = 1572864
static const size_t WS_F0     = WS_L2  + (size_t)3*256*32*64;        // 64*128*256    = 2097152
static const size_t WS_F1     = WS_F0  + (size_t)64*128*256;         // 128*64*128    = 1048576
static const size_t WS_F2     = WS_F1  + (size_t)128*64*128;         // 256*32*64     = 524288
static const size_t WS_W0P    = WS_F2  + (size_t)256*32*64;          // 64*576  bf16 -> 18432 floats
static const size_t WS_W1P    = WS_W0P + 18432;                      // 128*576 bf16 -> 36864 floats
static const size_t WS_W2P    = WS_W1P + 36864;                      // 256*1152 bf16 -> 147456 floats
static const size_t WS_STG    = WS_W2P + 147456;                     // shared NHWC bf16 staging (serial reuse)

__device__ inline unsigned short f2bf(float x) {
  unsigned u = __float_as_uint(x);
  unsigned r = ((u >> 16) & 1u) + 0x7FFFu;
  return (unsigned short)((u + r) >> 16);
}

__global__ void prep_k(const float* __restrict__ td, const float* __restrict__ ew,
                       const float* __restrict__ eb, float* __restrict__ scales) {
  int i = threadIdx.x;
  if (i < 5) {
    float e = tanhf(ew[0] * (1.0f / (td[i] + 0.1f)) + eb[0]) + 1.0f;
    // images fed to conv0: [x0, x1, x2, h0, h1] get [enw0, enw3, enw4, enw1, enw2]
    const int slot[5] = {0, 3, 4, 1, 2};
    scales[slot[i]] = e;
  }
}

// NCHW f32 -> NHWC bf16 (per 64-channel block), LDS tile transpose.
__global__ __launch_bounds__(256) void repack_k(const float* __restrict__ in,
                                                unsigned short* __restrict__ outh,
                                                int C, int H, int W) {
  __shared__ unsigned short lds[64 * 72];
  const int t = threadIdx.x;
  const int cbn = C >> 6;
  const int n  = blockIdx.z / cbn;
  const int cb = (blockIdx.z % cbn) << 6;
  const int h  = blockIdx.y;
  const int w0 = blockIdx.x << 6;
  const int wl = t & 63, cg = t >> 6;
  const float* ip = in + (((size_t)n * C + cb) * H + h) * W + w0;
#pragma unroll 4
  for (int cj = 0; cj < 16; ++cj) {
    int c = cg * 16 + cj;
    lds[wl * 72 + c] = f2bf(ip[(size_t)c * H * W + wl]);
  }
  __syncthreads();
  const int pw = t >> 2, ch = t & 3;
  unsigned short* op = outh + ((size_t)n * H * W + (size_t)h * W + w0 + pw) * C + cb;
#pragma unroll
  for (int it = 0; it < 2; ++it) {
    int c0 = (ch + it * 4) * 8;
    *(uint4*)(op + c0) = *(const uint4*)(lds + pw * 72 + c0);
  }
}

// Pack conv weights (Cout,Cin,3,3) f32 -> bf16 fragment order [cog][kstep][lane][8]
__global__ void pack_w_k(const float* __restrict__ W, unsigned short* __restrict__ wp,
                         int Cout, int Cin, int NK) {
  int t = blockIdx.x * 256 + threadIdx.x;
  if (t >= Cout * NK * 4) return;
  int co = t / (NK * 4); int rem = t - co * (NK * 4); int s = rem >> 2; int js = rem & 3;
  int cog = co >> 4; int l = js * 16 + (co & 15);
  unsigned short v[8];
#pragma unroll
  for (int j = 0; j < 8; ++j) {
    int k = s * 32 + js * 8 + j;
    int tap = k / Cin, ci = k - tap * Cin;
    int ky = tap / 3, kx = tap - ky * 3;
    v[j] = f2bf(W[(((size_t)co * Cin + ci) * 3 + ky) * 3 + kx]);
  }
  *(uint4*)(wp + ((size_t)(cog * NK + s) * 64 + l) * 8) = *(uint4*)v;
}

// 3x3 stride-2 pad-1 conv + scale + bias + relu via MFMA implicit GEMM.
template <int CIN, int COG>
__global__ __launch_bounds__(256) void conv_mfma_k(
    const unsigned short* __restrict__ inh, const unsigned short* __restrict__ wp,
    const float* __restrict__ bias, float* __restrict__ out,
    const float* __restrict__ scales, int Cout, int Hout, int Wout, int cogrp) {
  constexpr int NK = (9 * CIN) / 32;
  extern __shared__ unsigned short wlds[];
  const int tid = threadIdx.x, lane = tid & 63, wv = tid >> 6;
  const int Hin = Hout * 2, Win = Wout * 2;
  const int n   = blockIdx.z / cogrp;
  const int cg  = blockIdx.z % cogrp;
  const int co0 = cg * (COG * 16);
  const int h   = blockIdx.y;
  const int w0  = blockIdx.x * 64;

  {
    const float4* src = (const float4*)(wp + (size_t)(co0 >> 4) * NK * 64 * 8);
    float4* dst = (float4*)wlds;
    for (int i = tid; i < COG * NK * 64; i += 256) dst[i] = src[i];
  }
  __syncthreads();

  const int px = w0 + wv * 16 + (lane & 15);
  const int js = lane >> 4;
  const unsigned short* inp = inh + (size_t)n * CIN * Hin * Win;

  f32x4 acc[COG];
#pragma unroll
  for (int c = 0; c < COG; ++c) acc[c] = (f32x4){0.f, 0.f, 0.f, 0.f};

  const short8v bz = {0, 0, 0, 0, 0, 0, 0, 0};
  for (int s = 0; s < NK; ++s) {
    const int tap = (s * 32) / CIN;
    const int ci  = (s * 32) % CIN + js * 8;
    const int ky = tap / 3, kx = tap - ky * 3;
    const int iy = 2 * h + ky - 1;
    short8v b = bz;
    if (iy >= 0) {
      const int ix = 2 * px + kx - 1;
      const unsigned short* p = inp + ((size_t)iy * Win + (ix < 0 ? 0 : ix)) * CIN + ci;
      short8v v = *(const short8v*)p;
      if (ix >= 0) b = v;
    }
#pragma unroll
    for (int c = 0; c < COG; ++c) {
      short8v a = *(const short8v*)&wlds[((c * NK + s) * 64 + lane) * 8];
      acc[c] = __builtin_amdgcn_mfma_f32_16x16x32_bf16(a, b, acc[c], 0, 0, 0);
    }
  }

  const float sc = scales ? scales[n] : 1.0f;
#pragma unroll
  for (int c = 0; c < COG; ++c) {
#pragma unroll
    for (int r = 0; r < 4; ++r) {
      const int co = co0 + c * 16 + js * 4 + r;
      float v = fmaxf(acc[c][r] * sc + bias[co], 0.f);
      out[(((size_t)n * Cout + co) * Hout + h) * Wout + px] = v;
    }
  }
}

// Per-pixel 3-cav attention, register-resident single pass.
// C/16 lanes per pixel, 16 channels each, group-major lane layout.
template <int C>
__global__ __launch_bounds__(256) void fuse2_k(const float* __restrict__ in,
                                               float* __restrict__ out,
                                               int HW, float inv_sqrtC) {
  constexpr int LPP = C / 16;   // lanes per pixel (4/8/16)
  constexpr int PPW = 64 / LPP; // pixels per wave
  const int tid = threadIdx.x;
  const int lane = tid & 63, wv = tid >> 6;
  const int g = lane / PPW;                       // channel group
  const int p = blockIdx.x * (4 * PPW) + wv * PPW + (lane % PPW);
  const float* b0 = in + (size_t)(g * 16) * HW + p;
  const float* b1 = b0 + (size_t)C * HW;
  const float* b2 = b1 + (size_t)C * HW;
  float va[16], vb[16], vd[16];
  float d00 = 0.f, d01 = 0.f, d02 = 0.f;
#pragma unroll
  for (int j = 0; j < 16; ++j) {
    va[j] = b0[(size_t)j * HW];
    vb[j] = b1[(size_t)j * HW];
    vd[j] = b2[(size_t)j * HW];
    d00 += va[j] * va[j]; d01 += va[j] * vb[j]; d02 += va[j] * vd[j];
  }
#pragma unroll
  for (int off = PPW; off < 64; off <<= 1) {   // butterfly over channel groups only
    d00 += __shfl_xor(d00, off);
    d01 += __shfl_xor(d01, off);
    d02 += __shfl_xor(d02, off);
  }
  float s0 = d00 * inv_sqrtC, s1 = d01 * inv_sqrtC, s2 = d02 * inv_sqrtC;
  float m = fmaxf(s0, fmaxf(s1, s2));
  float e0 = expf(s0 - m), e1 = expf(s1 - m), e2 = expf(s2 - m);
  float inv = 1.0f / (e0 + e1 + e2);
  float a0 = e0 * inv, a1 = e1 * inv, a2 = e2 * inv;
  float* o0 = out + (size_t)(g * 16) * HW + p;
#pragma unroll
  for (int j = 0; j < 16; ++j)
    o0[(size_t)j * HW] = a0 * va[j] + a1 * vb[j] + a2 * vd[j];
}

// 1x1 conv: f (64, 32768) -> out (128, 32768).
__global__ __launch_bounds__(256) void up0_k(const float* __restrict__ f,
                                             const float* __restrict__ wgt,
                                             const float* __restrict__ bias,
                                             float* __restrict__ out) {
  const int tid = threadIdx.x, lane = tid & 63, og = tid >> 6;
  const int o0 = blockIdx.y * 16;
  const int p0 = blockIdx.x * 256 + lane;
  __shared__ float wl[64 * 16];
  for (int idx = tid; idx < 1024; idx += 256) {
    int os = idx >> 6, i = idx & 63;
    wl[i * 16 + os] = wgt[(size_t)(o0 + os) * 64 + i];
  }
  __syncthreads();
  float acc[4][4];
#pragma unroll
  for (int k = 0; k < 4; ++k)
#pragma unroll
    for (int j = 0; j < 4; ++j) acc[k][j] = 0.f;
  for (int i = 0; i < 64; ++i) {
    const float* fp = f + (size_t)i * HW0 + p0;
    float4 w4 = *(const float4*)&wl[i * 16 + og * 4];
    float fv[4];
#pragma unroll
    for (int k = 0; k < 4; ++k) fv[k] = fp[k * 64];
#pragma unroll
    for (int k = 0; k < 4; ++k) {
      acc[k][0] += fv[k] * w4.x; acc[k][1] += fv[k] * w4.y;
      acc[k][2] += fv[k] * w4.z; acc[k][3] += fv[k] * w4.w;
    }
  }
#pragma unroll
  for (int j = 0; j < 4; ++j) {
    const int o = o0 + og * 4 + j;
    const float b = bias[o];
    float* op = out + (size_t)o * HW0 + p0;
#pragma unroll
    for (int k = 0; k < 4; ++k) op[k * 64] = acc[k][j] + b;
  }
}

// 2x deconv (k=s=2): out[o,2h+r,2w+c] = b + sum_i f[i,h,w]*W[o,i,1-r,1-c]
__global__ __launch_bounds__(256) void up1_k(const float* __restrict__ f,
                                             const float* __restrict__ wgt,
                                             const float* __restrict__ bias,
                                             float* __restrict__ out) {
  const int tid = threadIdx.x, lane = tid & 63, og = tid >> 6;
  const int o0 = blockIdx.y * 8;
  const int h = blockIdx.x;
  const int c = lane & 1;
  const int wbase = lane >> 1;
  __shared__ float wl[128 * 4 * 8];
  for (int idx = tid; idx < 128 * 4 * 8; idx += 256) {
    int os = idx >> 9;
    int rem = idx & 511;
    int i = rem >> 2, rc = rem & 3;
    wl[(i * 4 + rc) * 8 + os] = wgt[((size_t)(o0 + os) * 128 + i) * 4 + rc];
  }
  __syncthreads();
  float acc[2][2][4];
#pragma unroll
  for (int j = 0; j < 2; ++j)
#pragma unroll
    for (int r = 0; r < 2; ++r)
#pragma unroll
      for (int k = 0; k < 4; ++k) acc[j][r][k] = 0.f;
  const int rc_r0 = 2 + (1 - c);
  const int rc_r1 = (1 - c);
  for (int i = 0; i < 128; ++i) {
    const float* frow = f + ((size_t)i * 64 + h) * 128;
    float fv[4];
#pragma unroll
    for (int k = 0; k < 4; ++k) fv[k] = frow[wbase + 32 * k];
    float2 w0 = *(const float2*)&wl[(i * 4 + rc_r0) * 8 + og * 2];
    float2 w1 = *(const float2*)&wl[(i * 4 + rc_r1) * 8 + og * 2];
#pragma unroll
    for (int k = 0; k < 4; ++k) {
      acc[0][0][k] += fv[k] * w0.x; acc[1][0][k] += fv[k] * w0.y;
      acc[0][1][k] += fv[k] * w1.x; acc[1][1][k] += fv[k] * w1.y;
    }
  }
#pragma unroll
  for (int j = 0; j < 2; ++j) {
    const int o = o0 + og * 2 + j;
    const float b = bias[o];
#pragma unroll
    for (int r = 0; r < 2; ++r) {
      float* op = out + (size_t)o * HW0 + (size_t)(2 * h + r) * 256 + lane;
#pragma unroll
      for (int k = 0; k < 4; ++k) op[64 * k] = acc[j][r][k] + b;
    }
  }
}

// 4x deconv (k=s=4): out[o,4h+r,4w+c] = b + sum_i f[i,h,w]*W[o,i,3-r,3-c]
__global__ __launch_bounds__(256) void up2_k(const float* __restrict__ f,
                                             const float* __restrict__ wgt,
                                             const float* __restrict__ bias,
                                             float* __restrict__ out) {
  const int tid = threadIdx.x, lane = tid & 63, og = tid >> 6;
  const int o0 = blockIdx.y * 4;
  const int h = blockIdx.x;
  const int c = lane & 3;
  const int wbase = lane >> 2;
  __shared__ float wl[256 * 16 * 4];
  for (int idx = tid; idx < 256 * 16 * 4; idx += 256) {
    int os = idx >> 12;
    int rem = idx & 4095;
    int i = rem >> 4, rc = rem & 15;
    wl[(i * 16 + rc) * 4 + os] = wgt[((size_t)(o0 + os) * 256 + i) * 16 + rc];
  }
  __syncthreads();
  float acc[4][4];
#pragma unroll
  for (int r = 0; r < 4; ++r)
#pragma unroll
    for (int k = 0; k < 4; ++k) acc[r][k] = 0.f;
  for (int i = 0; i < 256; ++i) {
    const float* frow = f + ((size_t)i * 32 + h) * 64;
    float fv[4];
#pragma unroll
    for (int k = 0; k < 4; ++k) fv[k] = frow[wbase + 16 * k];
    float wv[4];
#pragma unroll
    for (int r = 0; r < 4; ++r) wv[r] = wl[(i * 16 + (3 - r) * 4 + (3 - c)) * 4 + og];
#pragma unroll
    for (int r = 0; r < 4; ++r)
#pragma unroll
      for (int k = 0; k < 4; ++k) acc[r][k] += fv[k] * wv[r];
  }
  const int o = o0 + og;
  const float b = bias[o];
#pragma unroll
  for (int r = 0; r < 4; ++r) {
    float* op = out + (size_t)o * HW0 + (size_t)(4 * h + r) * 256 + lane;
#pragma unroll
    for (int k = 0; k < 4; ++k) op[64 * k] = acc[r][k] + b;
  }
}

// per-channel mean & max over 32768 pixels of x_fuse
__global__ __launch_bounds__(256) void sta_reduce_k(const float* __restrict__ xf,
                                                    float* __restrict__ mean,
                                                    float* __restrict__ mx) {
  const int c = blockIdx.x;
  const float* p = xf + (size_t)c * HW0;
  float s = 0.f, m = -1e30f;
  for (int i = threadIdx.x * 4; i < HW0; i += 1024) {
    float4 v = *(const float4*)(p + i);
    s += v.x + v.y + v.z + v.w;
    m = fmaxf(m, fmaxf(fmaxf(v.x, v.y), fmaxf(v.z, v.w)));
  }
#pragma unroll
  for (int off = 32; off; off >>= 1) {
    s += __shfl_down(s, off);
    m = fmaxf(m, __shfl_down(m, off));
  }
  __shared__ float ss[4], sm[4];
  if ((threadIdx.x & 63) == 0) { ss[threadIdx.x >> 6] = s; sm[threadIdx.x >> 6] = m; }
  __syncthreads();
  if (threadIdx.x == 0) {
    float S = ss[0] + ss[1] + ss[2] + ss[3];
    float M = fmaxf(fmaxf(sm[0], sm[1]), fmaxf(sm[2], sm[3]));
    mean[c] = S * (1.0f / 32768.0f);
    mx[c] = M;
  }
}

__global__ void sta_gate_k(const float* __restrict__ mean, const float* __restrict__ mx,
                           const float* __restrict__ w1, const float* __restrict__ w2,
                           float* __restrict__ gate) {
  __shared__ float havg[32], hmax[32];
  const int t = threadIdx.x;
  if (t < 32) {
    float sa = 0.f, sm = 0.f;
    for (int cc = 0; cc < 512; ++cc) {
      float w = w1[t * 512 + cc];
      sa += mean[cc] * w;
      sm += mx[cc] * w;
    }
    havg[t] = fmaxf(sa, 0.f);
    hmax[t] = fmaxf(sm, 0.f);
  }
  __syncthreads();
  float g = 0.f;
  for (int j = 0; j < 32; ++j) g += (havg[j] + hmax[j]) * w2[t * 32 + j];
  gate[t] = 1.0f / (1.0f + expf(-g));
}

__global__ __launch_bounds__(256) void sta_scale_k(float* __restrict__ xf,
                                                   const float* __restrict__ gate) {
  const size_t i = (size_t)(blockIdx.x * 256 + threadIdx.x) * 4;
  float4 v = *(const float4*)(xf + i);
  const float g = gate[i >> 15];
  v.x *= g; v.y *= g; v.z *= g; v.w *= g;
  *(float4*)(xf + i) = v;
}

extern "C" void kernel_launch(void* const* d_in, const int* in_sizes, int n_in,
                              void* d_out, int out_size, void* d_ws, size_t ws_size,
                              hipStream_t stream) {
  const float* x    = (const float*)d_in[0];   // (3,64,256,512)
  const float* hist = (const float*)d_in[1];   // (2,64,256,512)
  const float* td   = (const float*)d_in[4];   // (1,5)
  const float* ew   = (const float*)d_in[6];
  const float* eb   = (const float*)d_in[7];
  const float* b0w  = (const float*)d_in[8];
  const float* b0b  = (const float*)d_in[9];
  const float* b1w  = (const float*)d_in[10];
  const float* b1b  = (const float*)d_in[11];
  const float* b2w  = (const float*)d_in[12];
  const float* b2b  = (const float*)d_in[13];
  const float* d0w  = (const float*)d_in[14];
  const float* d0b  = (const float*)d_in[15];
  const float* d1w  = (const float*)d_in[16];
  const float* d1b  = (const float*)d_in[17];
  const float* d2w  = (const float*)d_in[18];
  const float* d2b  = (const float*)d_in[19];
  const float* w1   = (const float*)d_in[20];
  const float* w2   = (const float*)d_in[21];

  float* out = (float*)d_out;  // (512,128,256)
  float* ws  = (float*)d_ws;

  float* scales = ws + WS_SCALES;
  float* l0x = ws + WS_L0X;
  float* l1  = ws + WS_L1;
  float* l2  = ws + WS_L2;
  float* f0  = ws + WS_F0;
  float* f1  = ws + WS_F1;
  float* f2  = ws + WS_F2;
  unsigned short* w0p = (unsigned short*)(ws + WS_W0P);
  unsigned short* w1p = (unsigned short*)(ws + WS_W1P);
  unsigned short* w2p = (unsigned short*)(ws + WS_W2P);
  unsigned short* stg = (unsigned short*)(ws + WS_STG);  // serially reused NHWC bf16

  prep_k<<<1, 64, 0, stream>>>(td, ew, eb, scales);
  pack_w_k<<<18, 256, 0, stream>>>(b0w, w0p, 64, 64, 18);
  pack_w_k<<<36, 256, 0, stream>>>(b1w, w1p, 128, 64, 18);
  pack_w_k<<<144, 256, 0, stream>>>(b2w, w2p, 256, 128, 36);

  // ---- level 0 on x
  repack_k<<<dim3(8, 256, 3), 256, 0, stream>>>(x, stg, 64, 256, 512);
  conv_mfma_k<64, 4><<<dim3(4, 128, 3), 256, 73728, stream>>>(
      stg, w0p, b0b, l0x, scales, 64, 128, 256, 1);

  // ---- level 0 on historical
  repack_k<<<dim3(8, 256, 2), 256, 0, stream>>>(hist, stg, 64, 256, 512);
  conv_mfma_k<64, 4><<<dim3(4, 128, 2), 256, 73728, stream>>>(
      stg, w0p, b0b, out + (size_t)384 * HW0, scales + 3, 64, 128, 256, 1);

  fuse2_k<64><<<512, 256, 0, stream>>>(l0x, f0, 32768, 0.125f);
  up0_k<<<dim3(128, 8), 256, 0, stream>>>(f0, d0w, d0b, out);

  // ---- level 1
  repack_k<<<dim3(4, 128, 3), 256, 0, stream>>>(l0x, stg, 64, 128, 256);
  conv_mfma_k<64, 4><<<dim3(2, 64, 6), 256, 73728, stream>>>(
      stg, w1p, b1b, l1, nullptr, 128, 64, 128, 2);
  fuse2_k<128><<<256, 256, 0, stream>>>(l1, f1, 8192, 0.0883883476f);
  up1_k<<<dim3(64, 16), 256, 0, stream>>>(f1, d1w, d1b, out + (size_t)128 * HW0);

  // ---- level 2
  repack_k<<<dim3(2, 64, 6), 256, 0, stream>>>(l1, stg, 128, 64, 128);
  conv_mfma_k<128, 2><<<dim3(1, 32, 24), 256, 73728, stream>>>(
      stg, w2p, b2b, l2, nullptr, 256, 32, 64, 8);
  fuse2_k<256><<<128, 256, 0, stream>>>(l2, f2, 2048, 0.0625f);
  up2_k<<<dim3(32, 32), 256, 0, stream>>>(f2, d2w, d2b, out + (size_t)256 * HW0);

  // ---- STA gate
  sta_reduce_k<<<512, 256, 0, stream>>>(out, ws + WS_MEAN, ws + WS_MAX);
  sta_gate_k<<<1, 512, 0, stream>>>(ws + WS_MEAN, ws + WS_MAX, w1, w2, ws + WS_GATE);
  sta_scale_k<<<16384, 256, 0, stream>>>(out, ws + WS_GATE);
}

// Round 7
// 505.105 us; speedup vs baseline: 3.6326x; 1.1601x over previous
//
#include <hip/hip_runtime.h>
#include <math.h>

#define HW0 32768  // 128*256 output plane

typedef __attribute__((ext_vector_type(8))) short short8v;
typedef __attribute__((ext_vector_type(4))) float f32x4;

// workspace layout (floats)
static const size_t WS_SCALES = 0;                                   // 5
static const size_t WS_MEAN   = 64;                                  // 512
static const size_t WS_MAX    = 64 + 512;                            // 512
static const size_t WS_GATE   = 64 + 1024;                           // 512
static const size_t WS_L0X    = 2048;                                // 3*64*128*256   = 6291456
static const size_t WS_L1     = WS_L0X + (size_t)3*64*128*256;       // 3*128*64*128  = 3145728
static const size_t WS_L2     = WS_L1  + (size_t)3*128*64*128;       // 3*256*32*64   = 1572864
static const size_t WS_F0     = WS_L2  + (size_t)3*256*32*64;        // f0h bf16 (HW,64)  in 2097152-float slot
static const size_t WS_F1     = WS_F0  + (size_t)64*128*256;         // f1h bf16 (HW,128) in 1048576-float slot
static const size_t WS_F2     = WS_F1  + (size_t)128*64*128;         // f2h bf16 (HW,256) in 524288-float slot
static const size_t WS_W0P    = WS_F2  + (size_t)256*32*64;          // conv0 packed: 18432 floats
static const size_t WS_W1P    = WS_W0P + 18432;                      // conv1 packed: 36864 floats
static const size_t WS_W2P    = WS_W1P + 36864;                      // conv2 packed: 147456 floats
static const size_t WS_U0P    = WS_W2P + 147456;                     // up0 packed 128*64 bf16   -> 4096 floats
static const size_t WS_U1P    = WS_U0P + 4096;                       // up1 packed 512*128 bf16  -> 32768 floats
static const size_t WS_U2P    = WS_U1P + 32768;                      // up2 packed 2048*256 bf16 -> 262144 floats
static const size_t WS_STG    = WS_U2P + 262144;                     // shared NHWC bf16 staging (serial reuse)

__device__ inline unsigned short f2bf(float x) {
  unsigned u = __float_as_uint(x);
  unsigned r = ((u >> 16) & 1u) + 0x7FFFu;
  return (unsigned short)((u + r) >> 16);
}

__global__ void prep_k(const float* __restrict__ td, const float* __restrict__ ew,
                       const float* __restrict__ eb, float* __restrict__ scales) {
  int i = threadIdx.x;
  if (i < 5) {
    float e = tanhf(ew[0] * (1.0f / (td[i] + 0.1f)) + eb[0]) + 1.0f;
    // images fed to conv0: [x0, x1, x2, h0, h1] get [enw0, enw3, enw4, enw1, enw2]
    const int slot[5] = {0, 3, 4, 1, 2};
    scales[slot[i]] = e;
  }
}

// NCHW f32 -> NHWC bf16 (per 64-channel block), LDS tile transpose.
__global__ __launch_bounds__(256) void repack_k(const float* __restrict__ in,
                                                unsigned short* __restrict__ outh,
                                                int C, int H, int W) {
  __shared__ unsigned short lds[64 * 72];
  const int t = threadIdx.x;
  const int cbn = C >> 6;
  const int n  = blockIdx.z / cbn;
  const int cb = (blockIdx.z % cbn) << 6;
  const int h  = blockIdx.y;
  const int w0 = blockIdx.x << 6;
  const int wl = t & 63, cg = t >> 6;
  const float* ip = in + (((size_t)n * C + cb) * H + h) * W + w0;
#pragma unroll 4
  for (int cj = 0; cj < 16; ++cj) {
    int c = cg * 16 + cj;
    lds[wl * 72 + c] = f2bf(ip[(size_t)c * H * W + wl]);
  }
  __syncthreads();
  const int pw = t >> 2, ch = t & 3;
  unsigned short* op = outh + ((size_t)n * H * W + (size_t)h * W + w0 + pw) * C + cb;
#pragma unroll
  for (int it = 0; it < 2; ++it) {
    int c0 = (ch + it * 4) * 8;
    *(uint4*)(op + c0) = *(const uint4*)(lds + pw * 72 + c0);
  }
}

// Pack conv weights (Cout,Cin,3,3) f32 -> bf16 fragment order [cog][kstep][lane][8]
__global__ void pack_w_k(const float* __restrict__ W, unsigned short* __restrict__ wp,
                         int Cout, int Cin, int NK) {
  int t = blockIdx.x * 256 + threadIdx.x;
  if (t >= Cout * NK * 4) return;
  int co = t / (NK * 4); int rem = t - co * (NK * 4); int s = rem >> 2; int js = rem & 3;
  int cog = co >> 4; int l = js * 16 + (co & 15);
  unsigned short v[8];
#pragma unroll
  for (int j = 0; j < 8; ++j) {
    int k = s * 32 + js * 8 + j;
    int tap = k / Cin, ci = k - tap * Cin;
    int ky = tap / 3, kx = tap - ky * 3;
    v[j] = f2bf(W[(((size_t)co * Cin + ci) * 3 + ky) * 3 + kx]);
  }
  *(uint4*)(wp + ((size_t)(cog * NK + s) * 64 + l) * 8) = *(uint4*)v;
}

// Pack deconv/1x1 weights into A-fragment order for the up GEMMs.
// mode 0 (up0 1x1): m = o,                 src = W[m*K + k]
// mode 1 (up1 2x2): m = o*4 + r*2 + c,     src = W[(o*K+k)*4 + (1-r)*2 + (1-c)]
// mode 2 (up2 4x4): m = o*16 + r*4 + c,    src = W[(o*K+k)*16 + (3-r)*4 + (3-c)]
__global__ void pack_dw_k(const float* __restrict__ W, unsigned short* __restrict__ wp,
                          int M, int K, int NK, int mode) {
  int t = blockIdx.x * 256 + threadIdx.x;
  if (t >= M * NK * 4) return;
  int m = t / (NK * 4); int rem = t - m * (NK * 4); int s = rem >> 2; int js = rem & 3;
  int mt = m >> 4; int l = js * 16 + (m & 15);
  unsigned short v[8];
#pragma unroll
  for (int j = 0; j < 8; ++j) {
    int k = s * 32 + js * 8 + j;
    size_t idx;
    if (mode == 0) {
      idx = (size_t)m * K + k;
    } else if (mode == 1) {
      int o = m >> 2, r = (m >> 1) & 1, c = m & 1;
      idx = ((size_t)o * K + k) * 4 + (1 - r) * 2 + (1 - c);
    } else {
      int o = m >> 4, r = (m >> 2) & 3, c = m & 3;
      idx = ((size_t)o * K + k) * 16 + (3 - r) * 4 + (3 - c);
    }
    v[j] = f2bf(W[idx]);
  }
  *(uint4*)(wp + ((size_t)(mt * NK + s) * 64 + l) * 8) = *(uint4*)v;
}

// 3x3 stride-2 pad-1 conv + scale + bias + relu via MFMA implicit GEMM.
template <int CIN, int COG>
__global__ __launch_bounds__(256) void conv_mfma_k(
    const unsigned short* __restrict__ inh, const unsigned short* __restrict__ wp,
    const float* __restrict__ bias, float* __restrict__ out,
    const float* __restrict__ scales, int Cout, int Hout, int Wout, int cogrp) {
  constexpr int NK = (9 * CIN) / 32;
  extern __shared__ unsigned short wlds[];
  const int tid = threadIdx.x, lane = tid & 63, wv = tid >> 6;
  const int Hin = Hout * 2, Win = Wout * 2;
  const int n   = blockIdx.z / cogrp;
  const int cg  = blockIdx.z % cogrp;
  const int co0 = cg * (COG * 16);
  const int h   = blockIdx.y;
  const int w0  = blockIdx.x * 64;

  {
    const float4* src = (const float4*)(wp + (size_t)(co0 >> 4) * NK * 64 * 8);
    float4* dst = (float4*)wlds;
    for (int i = tid; i < COG * NK * 64; i += 256) dst[i] = src[i];
  }
  __syncthreads();

  const int px = w0 + wv * 16 + (lane & 15);
  const int js = lane >> 4;
  const unsigned short* inp = inh + (size_t)n * CIN * Hin * Win;

  f32x4 acc[COG];
#pragma unroll
  for (int c = 0; c < COG; ++c) acc[c] = (f32x4){0.f, 0.f, 0.f, 0.f};

  const short8v bz = {0, 0, 0, 0, 0, 0, 0, 0};
  for (int s = 0; s < NK; ++s) {
    const int tap = (s * 32) / CIN;
    const int ci  = (s * 32) % CIN + js * 8;
    const int ky = tap / 3, kx = tap - ky * 3;
    const int iy = 2 * h + ky - 1;
    short8v b = bz;
    if (iy >= 0) {
      const int ix = 2 * px + kx - 1;
      const unsigned short* p = inp + ((size_t)iy * Win + (ix < 0 ? 0 : ix)) * CIN + ci;
      short8v v = *(const short8v*)p;
      if (ix >= 0) b = v;
    }
#pragma unroll
    for (int c = 0; c < COG; ++c) {
      short8v a = *(const short8v*)&wlds[((c * NK + s) * 64 + lane) * 8];
      acc[c] = __builtin_amdgcn_mfma_f32_16x16x32_bf16(a, b, acc[c], 0, 0, 0);
    }
  }

  const float sc = scales ? scales[n] : 1.0f;
#pragma unroll
  for (int c = 0; c < COG; ++c) {
#pragma unroll
    for (int r = 0; r < 4; ++r) {
      const int co = co0 + c * 16 + js * 4 + r;
      float v = fmaxf(acc[c][r] * sc + bias[co], 0.f);
      out[(((size_t)n * Cout + co) * Hout + h) * Wout + px] = v;
    }
  }
}

// Per-pixel 3-cav attention, register-resident; OUTPUT bf16 (HW, C) row-major
// (exactly the B-fragment layout the up GEMMs consume).
template <int C>
__global__ __launch_bounds__(256) void fuse2_k(const float* __restrict__ in,
                                               unsigned short* __restrict__ outh,
                                               int HW, float inv_sqrtC) {
  constexpr int LPP = C / 16;   // lanes per pixel (4/8/16)
  constexpr int PPW = 64 / LPP; // pixels per wave
  const int tid = threadIdx.x;
  const int lane = tid & 63, wv = tid >> 6;
  const int g = lane / PPW;                       // channel group
  const int p = blockIdx.x * (4 * PPW) + wv * PPW + (lane % PPW);
  const float* b0 = in + (size_t)(g * 16) * HW + p;
  const float* b1 = b0 + (size_t)C * HW;
  const float* b2 = b1 + (size_t)C * HW;
  float va[16], vb[16], vd[16];
  float d00 = 0.f, d01 = 0.f, d02 = 0.f;
#pragma unroll
  for (int j = 0; j < 16; ++j) {
    va[j] = b0[(size_t)j * HW];
    vb[j] = b1[(size_t)j * HW];
    vd[j] = b2[(size_t)j * HW];
    d00 += va[j] * va[j]; d01 += va[j] * vb[j]; d02 += va[j] * vd[j];
  }
#pragma unroll
  for (int off = PPW; off < 64; off <<= 1) {   // butterfly over channel groups only
    d00 += __shfl_xor(d00, off);
    d01 += __shfl_xor(d01, off);
    d02 += __shfl_xor(d02, off);
  }
  float s0 = d00 * inv_sqrtC, s1 = d01 * inv_sqrtC, s2 = d02 * inv_sqrtC;
  float m = fmaxf(s0, fmaxf(s1, s2));
  float e0 = expf(s0 - m), e1 = expf(s1 - m), e2 = expf(s2 - m);
  float inv = 1.0f / (e0 + e1 + e2);
  float a0 = e0 * inv, a1 = e1 * inv, a2 = e2 * inv;
  unsigned short tmp[16];
#pragma unroll
  for (int j = 0; j < 16; ++j)
    tmp[j] = f2bf(a0 * va[j] + a1 * vb[j] + a2 * vd[j]);
  unsigned short* o0 = outh + (size_t)p * C + g * 16;
  *(uint4*)(o0)     = *(const uint4*)(tmp);
  *(uint4*)(o0 + 8) = *(const uint4*)(tmp + 8);
}

// Upsampler GEMM via MFMA. fh: (HW, K) bf16; wp: packed A fragments.
// Block: 4 waves x 16 px = 64 px, MT m-tiles of 16 rows. grid (HW/64, Mtiles/MT).
// EPI 0: up0 1x1 -> out[o, px];   EPI 1: up1 2x -> out[o, 2h+r, 2w+c] (W=128);
// EPI 2: up2 4x -> out[o, 4h+js, 4w+reg] (W=64).
template <int K, int MT, int EPI>
__global__ __launch_bounds__(256) void up_mfma_k(
    const unsigned short* __restrict__ fh, const unsigned short* __restrict__ wp,
    const float* __restrict__ bias, float* __restrict__ out) {
  constexpr int NK = K / 32;
  extern __shared__ unsigned short wlds[];
  const int tid = threadIdx.x, lane = tid & 63, wv = tid >> 6;
  const int mt0 = blockIdx.y * MT;
  {
    const float4* src = (const float4*)(wp + (size_t)mt0 * NK * 64 * 8);
    float4* dst = (float4*)wlds;
    for (int i = tid; i < MT * NK * 64; i += 256) dst[i] = src[i];
  }
  __syncthreads();

  const int px = blockIdx.x * 64 + wv * 16 + (lane & 15);
  const int js = lane >> 4;
  const unsigned short* bp = fh + (size_t)px * K + js * 8;

  f32x4 acc[MT];
#pragma unroll
  for (int t = 0; t < MT; ++t) acc[t] = (f32x4){0.f, 0.f, 0.f, 0.f};

#pragma unroll
  for (int s = 0; s < NK; ++s) {
    short8v b = *(const short8v*)(bp + s * 32);
#pragma unroll
    for (int t = 0; t < MT; ++t) {
      short8v a = *(const short8v*)&wlds[((t * NK + s) * 64 + lane) * 8];
      acc[t] = __builtin_amdgcn_mfma_f32_16x16x32_bf16(a, b, acc[t], 0, 0, 0);
    }
  }

  if constexpr (EPI == 0) {
#pragma unroll
    for (int t = 0; t < MT; ++t) {
      const int o = (mt0 + t) * 16 + js * 4;
#pragma unroll
      for (int r = 0; r < 4; ++r)
        out[(size_t)(o + r) * HW0 + px] = acc[t][r] + bias[o + r];
    }
  } else if constexpr (EPI == 1) {
    const int h = px >> 7, w = px & 127;
#pragma unroll
    for (int t = 0; t < MT; ++t) {
      const int o = (mt0 + t) * 4 + js;
      const float b = bias[o];
      float* base = out + (size_t)o * HW0 + (size_t)(2 * h) * 256 + 2 * w;
      *(float2*)base         = make_float2(acc[t][0] + b, acc[t][1] + b);
      *(float2*)(base + 256) = make_float2(acc[t][2] + b, acc[t][3] + b);
    }
  } else {
    const int h = px >> 6, w = px & 63;
#pragma unroll
    for (int t = 0; t < MT; ++t) {
      const int o = mt0 + t;
      const float b = bias[o];
      float4 v = make_float4(acc[t][0] + b, acc[t][1] + b, acc[t][2] + b, acc[t][3] + b);
      *(float4*)(out + (size_t)o * HW0 + (size_t)(4 * h + js) * 256 + 4 * w) = v;
    }
  }
}

// per-channel mean & max over 32768 pixels of x_fuse
__global__ __launch_bounds__(256) void sta_reduce_k(const float* __restrict__ xf,
                                                    float* __restrict__ mean,
                                                    float* __restrict__ mx) {
  const int c = blockIdx.x;
  const float* p = xf + (size_t)c * HW0;
  float s = 0.f, m = -1e30f;
  for (int i = threadIdx.x * 4; i < HW0; i += 1024) {
    float4 v = *(const float4*)(p + i);
    s += v.x + v.y + v.z + v.w;
    m = fmaxf(m, fmaxf(fmaxf(v.x, v.y), fmaxf(v.z, v.w)));
  }
#pragma unroll
  for (int off = 32; off; off >>= 1) {
    s += __shfl_down(s, off);
    m = fmaxf(m, __shfl_down(m, off));
  }
  __shared__ float ss[4], sm[4];
  if ((threadIdx.x & 63) == 0) { ss[threadIdx.x >> 6] = s; sm[threadIdx.x >> 6] = m; }
  __syncthreads();
  if (threadIdx.x == 0) {
    float S = ss[0] + ss[1] + ss[2] + ss[3];
    float M = fmaxf(fmaxf(sm[0], sm[1]), fmaxf(sm[2], sm[3]));
    mean[c] = S * (1.0f / 32768.0f);
    mx[c] = M;
  }
}

__global__ void sta_gate_k(const float* __restrict__ mean, const float* __restrict__ mx,
                           const float* __restrict__ w1, const float* __restrict__ w2,
                           float* __restrict__ gate) {
  __shared__ float havg[32], hmax[32];
  const int t = threadIdx.x;
  if (t < 32) {
    float sa = 0.f, sm = 0.f;
    for (int cc = 0; cc < 512; ++cc) {
      float w = w1[t * 512 + cc];
      sa += mean[cc] * w;
      sm += mx[cc] * w;
    }
    havg[t] = fmaxf(sa, 0.f);
    hmax[t] = fmaxf(sm, 0.f);
  }
  __syncthreads();
  float g = 0.f;
  for (int j = 0; j < 32; ++j) g += (havg[j] + hmax[j]) * w2[t * 32 + j];
  gate[t] = 1.0f / (1.0f + expf(-g));
}

__global__ __launch_bounds__(256) void sta_scale_k(float* __restrict__ xf,
                                                   const float* __restrict__ gate) {
  const size_t i = (size_t)(blockIdx.x * 256 + threadIdx.x) * 4;
  float4 v = *(const float4*)(xf + i);
  const float g = gate[i >> 15];
  v.x *= g; v.y *= g; v.z *= g; v.w *= g;
  *(float4*)(xf + i) = v;
}

extern "C" void kernel_launch(void* const* d_in, const int* in_sizes, int n_in,
                              void* d_out, int out_size, void* d_ws, size_t ws_size,
                              hipStream_t stream) {
  const float* x    = (const float*)d_in[0];   // (3,64,256,512)
  const float* hist = (const float*)d_in[1];   // (2,64,256,512)
  const float* td   = (const float*)d_in[4];   // (1,5)
  const float* ew   = (const float*)d_in[6];
  const float* eb   = (const float*)d_in[7];
  const float* b0w  = (const float*)d_in[8];
  const float* b0b  = (const float*)d_in[9];
  const float* b1w  = (const float*)d_in[10];
  const float* b1b  = (const float*)d_in[11];
  const float* b2w  = (const float*)d_in[12];
  const float* b2b  = (const float*)d_in[13];
  const float* d0w  = (const float*)d_in[14];
  const float* d0b  = (const float*)d_in[15];
  const float* d1w  = (const float*)d_in[16];
  const float* d1b  = (const float*)d_in[17];
  const float* d2w  = (const float*)d_in[18];
  const float* d2b  = (const float*)d_in[19];
  const float* w1   = (const float*)d_in[20];
  const float* w2   = (const float*)d_in[21];

  float* out = (float*)d_out;  // (512,128,256)
  float* ws  = (float*)d_ws;

  float* scales = ws + WS_SCALES;
  float* l0x = ws + WS_L0X;
  float* l1  = ws + WS_L1;
  float* l2  = ws + WS_L2;
  unsigned short* f0h = (unsigned short*)(ws + WS_F0);
  unsigned short* f1h = (unsigned short*)(ws + WS_F1);
  unsigned short* f2h = (unsigned short*)(ws + WS_F2);
  unsigned short* w0p = (unsigned short*)(ws + WS_W0P);
  unsigned short* w1p = (unsigned short*)(ws + WS_W1P);
  unsigned short* w2p = (unsigned short*)(ws + WS_W2P);
  unsigned short* u0p = (unsigned short*)(ws + WS_U0P);
  unsigned short* u1p = (unsigned short*)(ws + WS_U1P);
  unsigned short* u2p = (unsigned short*)(ws + WS_U2P);
  unsigned short* stg = (unsigned short*)(ws + WS_STG);  // serially reused NHWC bf16

  prep_k<<<1, 64, 0, stream>>>(td, ew, eb, scales);
  pack_w_k<<<18, 256, 0, stream>>>(b0w, w0p, 64, 64, 18);
  pack_w_k<<<36, 256, 0, stream>>>(b1w, w1p, 128, 64, 18);
  pack_w_k<<<144, 256, 0, stream>>>(b2w, w2p, 256, 128, 36);
  pack_dw_k<<<4, 256, 0, stream>>>(d0w, u0p, 128, 64, 2, 0);
  pack_dw_k<<<32, 256, 0, stream>>>(d1w, u1p, 512, 128, 4, 1);
  pack_dw_k<<<256, 256, 0, stream>>>(d2w, u2p, 2048, 256, 8, 2);

  // ---- level 0 on x
  repack_k<<<dim3(8, 256, 3), 256, 0, stream>>>(x, stg, 64, 256, 512);
  conv_mfma_k<64, 4><<<dim3(4, 128, 3), 256, 73728, stream>>>(
      stg, w0p, b0b, l0x, scales, 64, 128, 256, 1);

  // ---- level 0 on historical
  repack_k<<<dim3(8, 256, 2), 256, 0, stream>>>(hist, stg, 64, 256, 512);
  conv_mfma_k<64, 4><<<dim3(4, 128, 2), 256, 73728, stream>>>(
      stg, w0p, b0b, out + (size_t)384 * HW0, scales + 3, 64, 128, 256, 1);

  fuse2_k<64><<<512, 256, 0, stream>>>(l0x, f0h, 32768, 0.125f);
  up_mfma_k<64, 8, 0><<<dim3(512, 1), 256, 16384, stream>>>(f0h, u0p, d0b, out);

  // ---- level 1
  repack_k<<<dim3(4, 128, 3), 256, 0, stream>>>(l0x, stg, 64, 128, 256);
  conv_mfma_k<64, 4><<<dim3(2, 64, 6), 256, 73728, stream>>>(
      stg, w1p, b1b, l1, nullptr, 128, 64, 128, 2);
  fuse2_k<128><<<256, 256, 0, stream>>>(l1, f1h, 8192, 0.0883883476f);
  up_mfma_k<128, 8, 1><<<dim3(128, 4), 256, 32768, stream>>>(
      f1h, u1p, d1b, out + (size_t)128 * HW0);

  // ---- level 2
  repack_k<<<dim3(2, 64, 6), 256, 0, stream>>>(l1, stg, 128, 64, 128);
  conv_mfma_k<128, 2><<<dim3(1, 32, 24), 256, 73728, stream>>>(
      stg, w2p, b2b, l2, nullptr, 256, 32, 64, 8);
  fuse2_k<256><<<128, 256, 0, stream>>>(l2, f2h, 2048, 0.0625f);
  up_mfma_k<256, 4, 2><<<dim3(32, 32), 256, 32768, stream>>>(
      f2h, u2p, d2b, out + (size_t)256 * HW0);

  // ---- STA gate
  sta_reduce_k<<<512, 256, 0, stream>>>(out, ws + WS_MEAN, ws + WS_MAX);
  sta_gate_k<<<1, 512, 0, stream>>>(ws + WS_MEAN, ws + WS_MAX, w1, w2, ws + WS_GATE);
  sta_scale_k<<<16384, 256, 0, stream>>>(out, ws + WS_GATE);
}

// Round 12
// 477.640 us; speedup vs baseline: 3.8415x; 1.0575x over previous
//
#include <hip/hip_runtime.h>
#include <math.h>

#define HW0 32768  // 128*256 output plane

typedef __attribute__((ext_vector_type(8))) short short8v;
typedef __attribute__((ext_vector_type(4))) float f32x4;

// workspace layout (floats)
static const size_t WS_SCALES = 0;                                   // 5
static const size_t WS_MEAN   = 64;                                  // 512
static const size_t WS_MAX    = 576;                                 // 512
static const size_t WS_GATE   = 1088;                                // 512
static const size_t WS_L0X    = 2048;                                // l0x NCHW f32: 3*64*128*256
static const size_t WS_L1     = WS_L0X + (size_t)3*64*128*256;       // l1 NCHW f32: 3*128*64*128
static const size_t WS_L2     = WS_L1  + (size_t)3*128*64*128;       // l2 NCHW f32: 3*256*32*64
static const size_t WS_F1     = WS_L2  + (size_t)3*256*32*64;        // f1h bf16 (8192,128) -> 524288 floats
static const size_t WS_F2     = WS_F1  + 524288;                     // f2h bf16 (2048,256) -> 262144 floats
static const size_t WS_W0P    = WS_F2  + 262144;                     // conv0 packed: 18432 floats
static const size_t WS_W1P    = WS_W0P + 18432;                      // conv1 packed: 36864 floats
static const size_t WS_W2P    = WS_W1P + 36864;                      // conv2 packed: 147456 floats
static const size_t WS_U0P    = WS_W2P + 147456;                     // up0 packed: 4096 floats
static const size_t WS_U1P    = WS_U0P + 4096;                       // up1 packed: 32768 floats
static const size_t WS_U2P    = WS_U1P + 32768;                      // up2 packed: 262144 floats
static const size_t WS_L0H    = WS_U2P + 262144;                     // l0h NHWC bf16: 3145728 floats
static const size_t WS_L1H    = WS_L0H + 3145728;                    // l1h NHWC bf16: 1572864 floats
static const size_t WS_STG    = WS_L1H + 1572864;                    // x/hist NHWC bf16 staging (serial reuse)

__device__ inline unsigned short f2bf(float x) {
  unsigned u = __float_as_uint(x);
  unsigned r = ((u >> 16) & 1u) + 0x7FFFu;
  return (unsigned short)((u + r) >> 16);
}

// ---- weight packing bodies (device) ----
__device__ inline void pack_w_body(int t, const float* __restrict__ W,
                                   unsigned short* __restrict__ wp,
                                   int Cout, int Cin, int NK) {
  if (t >= Cout * NK * 4) return;
  int co = t / (NK * 4); int rem = t - co * (NK * 4); int s = rem >> 2; int js = rem & 3;
  int cog = co >> 4; int l = js * 16 + (co & 15);
  unsigned short v[8];
#pragma unroll
  for (int j = 0; j < 8; ++j) {
    int k = s * 32 + js * 8 + j;
    int tap = k / Cin, ci = k - tap * Cin;
    int ky = tap / 3, kx = tap - ky * 3;
    v[j] = f2bf(W[(((size_t)co * Cin + ci) * 3 + ky) * 3 + kx]);
  }
  *(uint4*)(wp + ((size_t)(cog * NK + s) * 64 + l) * 8) = *(uint4*)v;
}

__device__ inline void pack_dw_body(int t, const float* __restrict__ W,
                                    unsigned short* __restrict__ wp,
                                    int M, int K, int NK, int mode) {
  if (t >= M * NK * 4) return;
  int m = t / (NK * 4); int rem = t - m * (NK * 4); int s = rem >> 2; int js = rem & 3;
  int mt = m >> 4; int l = js * 16 + (m & 15);
  unsigned short v[8];
#pragma unroll
  for (int j = 0; j < 8; ++j) {
    int k = s * 32 + js * 8 + j;
    size_t idx;
    if (mode == 0) {
      idx = (size_t)m * K + k;
    } else if (mode == 1) {
      int o = m >> 2, r = (m >> 1) & 1, c = m & 1;
      idx = ((size_t)o * K + k) * 4 + (1 - r) * 2 + (1 - c);
    } else {
      int o = m >> 4, r = (m >> 2) & 3, c = m & 3;
      idx = ((size_t)o * K + k) * 16 + (3 - r) * 4 + (3 - c);
    }
    v[j] = f2bf(W[idx]);
  }
  *(uint4*)(wp + ((size_t)(mt * NK + s) * 64 + l) * 8) = *(uint4*)v;
}

// One launch: prep scales + all 6 weight packs, dispatched by block range.
__global__ __launch_bounds__(256) void pack_all_k(
    const float* __restrict__ td, const float* __restrict__ ew,
    const float* __restrict__ eb, float* __restrict__ scales,
    const float* __restrict__ b0w, unsigned short* __restrict__ w0p,
    const float* __restrict__ b1w, unsigned short* __restrict__ w1p,
    const float* __restrict__ b2w, unsigned short* __restrict__ w2p,
    const float* __restrict__ d0w, unsigned short* __restrict__ u0p,
    const float* __restrict__ d1w, unsigned short* __restrict__ u1p,
    const float* __restrict__ d2w, unsigned short* __restrict__ u2p) {
  const int b = blockIdx.x, tid = threadIdx.x;
  if (b == 0) {
    if (tid < 5) {
      float e = tanhf(ew[0] * (1.0f / (td[tid] + 0.1f)) + eb[0]) + 1.0f;
      const int slot[5] = {0, 3, 4, 1, 2};  // [x0,x1,x2,h0,h1] <- enw[0,3,4,1,2]
      scales[slot[tid]] = e;
    }
  } else if (b < 19) {
    pack_w_body((b - 1) * 256 + tid, b0w, w0p, 64, 64, 18);
  } else if (b < 55) {
    pack_w_body((b - 19) * 256 + tid, b1w, w1p, 128, 64, 18);
  } else if (b < 199) {
    pack_w_body((b - 55) * 256 + tid, b2w, w2p, 256, 128, 36);
  } else if (b < 203) {
    pack_dw_body((b - 199) * 256 + tid, d0w, u0p, 128, 64, 2, 0);
  } else if (b < 235) {
    pack_dw_body((b - 203) * 256 + tid, d1w, u1p, 512, 128, 4, 1);
  } else {
    pack_dw_body((b - 235) * 256 + tid, d2w, u2p, 2048, 256, 8, 2);
  }
}

// NCHW f32 -> NHWC bf16 (per 64-channel block), LDS tile transpose.
__global__ __launch_bounds__(256) void repack_k(const float* __restrict__ in,
                                                unsigned short* __restrict__ outh,
                                                int C, int H, int W) {
  __shared__ unsigned short lds[64 * 72];
  const int t = threadIdx.x;
  const int cbn = C >> 6;
  const int n  = blockIdx.z / cbn;
  const int cb = (blockIdx.z % cbn) << 6;
  const int h  = blockIdx.y;
  const int w0 = blockIdx.x << 6;
  const int wl = t & 63, cg = t >> 6;
  const float* ip = in + (((size_t)n * C + cb) * H + h) * W + w0;
#pragma unroll 4
  for (int cj = 0; cj < 16; ++cj) {
    int c = cg * 16 + cj;
    lds[wl * 72 + c] = f2bf(ip[(size_t)c * H * W + wl]);
  }
  __syncthreads();
  const int pw = t >> 2, ch = t & 3;
  unsigned short* op = outh + ((size_t)n * H * W + (size_t)h * W + w0 + pw) * C + cb;
#pragma unroll
  for (int it = 0; it < 2; ++it) {
    int c0 = (ch + it * 4) * 8;
    *(uint4*)(op + c0) = *(const uint4*)(lds + pw * 72 + c0);
  }
}

// 3x3 stride-2 pad-1 conv + scale + bias + relu via MFMA implicit GEMM.
// Optionally ALSO writes the result as NHWC bf16 (outh) for the next conv level.
template <int CIN, int COG>
__global__ __launch_bounds__(256) void conv_mfma_k(
    const unsigned short* __restrict__ inh, const unsigned short* __restrict__ wp,
    const float* __restrict__ bias, float* __restrict__ out,
    unsigned short* __restrict__ outh,
    const float* __restrict__ scales, int Cout, int Hout, int Wout, int cogrp) {
  constexpr int NK = (9 * CIN) / 32;
  extern __shared__ unsigned short wlds[];
  const int tid = threadIdx.x, lane = tid & 63, wv = tid >> 6;
  const int Hin = Hout * 2, Win = Wout * 2;
  const int n   = blockIdx.z / cogrp;
  const int cg  = blockIdx.z % cogrp;
  const int co0 = cg * (COG * 16);
  const int h   = blockIdx.y;
  const int w0  = blockIdx.x * 64;

  {
    const float4* src = (const float4*)(wp + (size_t)(co0 >> 4) * NK * 64 * 8);
    float4* dst = (float4*)wlds;
    for (int i = tid; i < COG * NK * 64; i += 256) dst[i] = src[i];
  }
  __syncthreads();

  const int px = w0 + wv * 16 + (lane & 15);
  const int js = lane >> 4;
  const unsigned short* inp = inh + (size_t)n * CIN * Hin * Win;

  f32x4 acc[COG];
#pragma unroll
  for (int c = 0; c < COG; ++c) acc[c] = (f32x4){0.f, 0.f, 0.f, 0.f};

  const short8v bz = {0, 0, 0, 0, 0, 0, 0, 0};
  for (int s = 0; s < NK; ++s) {
    const int tap = (s * 32) / CIN;
    const int ci  = (s * 32) % CIN + js * 8;
    const int ky = tap / 3, kx = tap - ky * 3;
    const int iy = 2 * h + ky - 1;
    short8v b = bz;
    if (iy >= 0) {
      const int ix = 2 * px + kx - 1;
      const unsigned short* p = inp + ((size_t)iy * Win + (ix < 0 ? 0 : ix)) * CIN + ci;
      short8v v = *(const short8v*)p;
      if (ix >= 0) b = v;
    }
#pragma unroll
    for (int c = 0; c < COG; ++c) {
      short8v a = *(const short8v*)&wlds[((c * NK + s) * 64 + lane) * 8];
      acc[c] = __builtin_amdgcn_mfma_f32_16x16x32_bf16(a, b, acc[c], 0, 0, 0);
    }
  }

  const float sc = scales ? scales[n] : 1.0f;
  unsigned short* oph = outh
      ? outh + ((size_t)n * Hout * Wout + (size_t)h * Wout + px) * Cout + co0
      : nullptr;
#pragma unroll
  for (int c = 0; c < COG; ++c) {
    float vv[4];
#pragma unroll
    for (int r = 0; r < 4; ++r) {
      const int co = co0 + c * 16 + js * 4 + r;
      vv[r] = fmaxf(acc[c][r] * sc + bias[co], 0.f);
      out[(((size_t)n * Cout + co) * Hout + h) * Wout + px] = vv[r];
    }
    if (oph) {
      unsigned short hv[4] = {f2bf(vv[0]), f2bf(vv[1]), f2bf(vv[2]), f2bf(vv[3])};
      *(uint2*)(oph + c * 16 + js * 4) = *(const uint2*)hv;
    }
  }
}

// Per-pixel 3-cav attention, register-resident; OUTPUT bf16 (HW, C) row-major.
template <int C>
__global__ __launch_bounds__(256) void fuse2_k(const float* __restrict__ in,
                                               unsigned short* __restrict__ outh,
                                               int HW, float inv_sqrtC) {
  constexpr int LPP = C / 16;
  constexpr int PPW = 64 / LPP;
  const int tid = threadIdx.x;
  const int lane = tid & 63, wv = tid >> 6;
  const int g = lane / PPW;
  const int p = blockIdx.x * (4 * PPW) + wv * PPW + (lane % PPW);
  const float* b0 = in + (size_t)(g * 16) * HW + p;
  const float* b1 = b0 + (size_t)C * HW;
  const float* b2 = b1 + (size_t)C * HW;
  float va[16], vb[16], vd[16];
  float d00 = 0.f, d01 = 0.f, d02 = 0.f;
#pragma unroll
  for (int j = 0; j < 16; ++j) {
    va[j] = b0[(size_t)j * HW];
    vb[j] = b1[(size_t)j * HW];
    vd[j] = b2[(size_t)j * HW];
    d00 += va[j] * va[j]; d01 += va[j] * vb[j]; d02 += va[j] * vd[j];
  }
#pragma unroll
  for (int off = PPW; off < 64; off <<= 1) {
    d00 += __shfl_xor(d00, off);
    d01 += __shfl_xor(d01, off);
    d02 += __shfl_xor(d02, off);
  }
  float s0 = d00 * inv_sqrtC, s1 = d01 * inv_sqrtC, s2 = d02 * inv_sqrtC;
  float m = fmaxf(s0, fmaxf(s1, s2));
  float e0 = expf(s0 - m), e1 = expf(s1 - m), e2 = expf(s2 - m);
  float inv = 1.0f / (e0 + e1 + e2);
  float a0 = e0 * inv, a1 = e1 * inv, a2 = e2 * inv;
  unsigned short tmp[16];
#pragma unroll
  for (int j = 0; j < 16; ++j)
    tmp[j] = f2bf(a0 * va[j] + a1 * vb[j] + a2 * vd[j]);
  unsigned short* o0 = outh + (size_t)p * C + g * 16;
  *(uint4*)(o0)     = *(const uint4*)(tmp);
  *(uint4*)(o0 + 8) = *(const uint4*)(tmp + 8);
}

// Fused level-0 attention + 1x1 up-conv. Block = 64 px, 4 waves.
// Fuse values go regs -> XOR-swizzled LDS -> MFMA B fragments (M=128, K=64).
__global__ __launch_bounds__(256) void fuse_up0_k(const float* __restrict__ in,
                                                  const unsigned short* __restrict__ wp,
                                                  const float* __restrict__ bias,
                                                  float* __restrict__ out) {
  __shared__ unsigned short wlds[8192];   // 8 mtiles x NK=2 x 64 lanes x 8
  __shared__ unsigned short pbuf[4096];   // 64 px x 64 ci bf16, swizzled
  const int tid = threadIdx.x, lane = tid & 63, wv = tid >> 6;
  {
    const uint4* src = (const uint4*)wp;
    uint4* dst = (uint4*)wlds;
    for (int i = tid; i < 1024; i += 256) dst[i] = src[i];
  }
  const int g = lane >> 4;                 // channel group (fuse)
  const int pl = wv * 16 + (lane & 15);    // block-local pixel
  const int p = blockIdx.x * 64 + pl;
  const float* b0 = in + (size_t)(g * 16) * HW0 + p;
  const float* b1 = b0 + (size_t)64 * HW0;
  const float* b2 = b1 + (size_t)64 * HW0;
  float va[16], vb[16], vd[16];
  float d00 = 0.f, d01 = 0.f, d02 = 0.f;
#pragma unroll
  for (int j = 0; j < 16; ++j) {
    va[j] = b0[(size_t)j * HW0];
    vb[j] = b1[(size_t)j * HW0];
    vd[j] = b2[(size_t)j * HW0];
    d00 += va[j] * va[j]; d01 += va[j] * vb[j]; d02 += va[j] * vd[j];
  }
#pragma unroll
  for (int off = 16; off < 64; off <<= 1) {
    d00 += __shfl_xor(d00, off);
    d01 += __shfl_xor(d01, off);
    d02 += __shfl_xor(d02, off);
  }
  float s0 = d00 * 0.125f, s1 = d01 * 0.125f, s2 = d02 * 0.125f;
  float m = fmaxf(s0, fmaxf(s1, s2));
  float e0 = expf(s0 - m), e1 = expf(s1 - m), e2 = expf(s2 - m);
  float inv = 1.0f / (e0 + e1 + e2);
  float a0 = e0 * inv, a1 = e1 * inv, a2 = e2 * inv;
  unsigned short tmp[16];
#pragma unroll
  for (int j = 0; j < 16; ++j)
    tmp[j] = f2bf(a0 * va[j] + a1 * vb[j] + a2 * vd[j]);
  const unsigned swz = (unsigned)((pl & 7) << 4);
  const unsigned base = (unsigned)(pl * 128 + g * 32);
  *(uint4*)((char*)pbuf + (base ^ swz))        = *(const uint4*)tmp;
  *(uint4*)((char*)pbuf + ((base + 16) ^ swz)) = *(const uint4*)(tmp + 8);
  __syncthreads();

  const int js = lane >> 4;
  f32x4 acc[8];
#pragma unroll
  for (int t = 0; t < 8; ++t) acc[t] = (f32x4){0.f, 0.f, 0.f, 0.f};
#pragma unroll
  for (int s = 0; s < 2; ++s) {
    const unsigned rb = (unsigned)(pl * 128 + (s * 32 + js * 8) * 2) ^ swz;
    short8v b = *(const short8v*)((const char*)pbuf + rb);
#pragma unroll
    for (int t = 0; t < 8; ++t) {
      short8v a = *(const short8v*)&wlds[((t * 2 + s) * 64 + lane) * 8];
      acc[t] = __builtin_amdgcn_mfma_f32_16x16x32_bf16(a, b, acc[t], 0, 0, 0);
    }
  }
#pragma unroll
  for (int t = 0; t < 8; ++t) {
    const int o = t * 16 + js * 4;
#pragma unroll
    for (int r = 0; r < 4; ++r)
      out[(size_t)(o + r) * HW0 + p] = acc[t][r] + bias[o + r];
  }
}

// Upsampler GEMM via MFMA. fh: (HW, K) bf16; wp: packed A fragments.
// EPI 1: up1 2x -> out[o, 2h+r, 2w+c] (W=128); EPI 2: up2 4x -> out[o, 4h+js, 4w+reg] (W=64).
template <int K, int MT, int EPI>
__global__ __launch_bounds__(256) void up_mfma_k(
    const unsigned short* __restrict__ fh, const unsigned short* __restrict__ wp,
    const float* __restrict__ bias, float* __restrict__ out) {
  constexpr int NK = K / 32;
  extern __shared__ unsigned short uplds[];
  const int tid = threadIdx.x, lane = tid & 63, wv = tid >> 6;
  const int mt0 = blockIdx.y * MT;
  {
    const float4* src = (const float4*)(wp + (size_t)mt0 * NK * 64 * 8);
    float4* dst = (float4*)uplds;
    for (int i = tid; i < MT * NK * 64; i += 256) dst[i] = src[i];
  }
  __syncthreads();

  const int px = blockIdx.x * 64 + wv * 16 + (lane & 15);
  const int js = lane >> 4;
  const unsigned short* bp = fh + (size_t)px * K + js * 8;

  f32x4 acc[MT];
#pragma unroll
  for (int t = 0; t < MT; ++t) acc[t] = (f32x4){0.f, 0.f, 0.f, 0.f};

#pragma unroll
  for (int s = 0; s < NK; ++s) {
    short8v b = *(const short8v*)(bp + s * 32);
#pragma unroll
    for (int t = 0; t < MT; ++t) {
      short8v a = *(const short8v*)&uplds[((t * NK + s) * 64 + lane) * 8];
      acc[t] = __builtin_amdgcn_mfma_f32_16x16x32_bf16(a, b, acc[t], 0, 0, 0);
    }
  }

  if constexpr (EPI == 1) {
    const int h = px >> 7, w = px & 127;
#pragma unroll
    for (int t = 0; t < MT; ++t) {
      const int o = (mt0 + t) * 4 + js;
      const float b = bias[o];
      float* base = out + (size_t)o * HW0 + (size_t)(2 * h) * 256 + 2 * w;
      *(float2*)base         = make_float2(acc[t][0] + b, acc[t][1] + b);
      *(float2*)(base + 256) = make_float2(acc[t][2] + b, acc[t][3] + b);
    }
  } else {
    const int h = px >> 6, w = px & 63;
#pragma unroll
    for (int t = 0; t < MT; ++t) {
      const int o = mt0 + t;
      const float b = bias[o];
      float4 v = make_float4(acc[t][0] + b, acc[t][1] + b, acc[t][2] + b, acc[t][3] + b);
      *(float4*)(out + (size_t)o * HW0 + (size_t)(4 * h + js) * 256 + 4 * w) = v;
    }
  }
}

// per-channel mean & max over 32768 pixels of x_fuse
__global__ __launch_bounds__(256) void sta_reduce_k(const float* __restrict__ xf,
                                                    float* __restrict__ mean,
                                                    float* __restrict__ mx) {
  const int c = blockIdx.x;
  const float* p = xf + (size_t)c * HW0;
  float s = 0.f, m = -1e30f;
  for (int i = threadIdx.x * 4; i < HW0; i += 1024) {
    float4 v = *(const float4*)(p + i);
    s += v.x + v.y + v.z + v.w;
    m = fmaxf(m, fmaxf(fmaxf(v.x, v.y), fmaxf(v.z, v.w)));
  }
#pragma unroll
  for (int off = 32; off; off >>= 1) {
    s += __shfl_down(s, off);
    m = fmaxf(m, __shfl_down(m, off));
  }
  __shared__ float ss[4], sm[4];
  if ((threadIdx.x & 63) == 0) { ss[threadIdx.x >> 6] = s; sm[threadIdx.x >> 6] = m; }
  __syncthreads();
  if (threadIdx.x == 0) {
    float S = ss[0] + ss[1] + ss[2] + ss[3];
    float M = fmaxf(fmaxf(sm[0], sm[1]), fmaxf(sm[2], sm[3]));
    mean[c] = S * (1.0f / 32768.0f);
    mx[c] = M;
  }
}

__global__ void sta_gate_k(const float* __restrict__ mean, const float* __restrict__ mx,
                           const float* __restrict__ w1, const float* __restrict__ w2,
                           float* __restrict__ gate) {
  __shared__ float havg[32], hmax[32];
  const int t = threadIdx.x;
  if (t < 32) {
    float sa = 0.f, sm = 0.f;
    for (int cc = 0; cc < 512; ++cc) {
      float w = w1[t * 512 + cc];
      sa += mean[cc] * w;
      sm += mx[cc] * w;
    }
    havg[t] = fmaxf(sa, 0.f);
    hmax[t] = fmaxf(sm, 0.f);
  }
  __syncthreads();
  float g = 0.f;
  for (int j = 0; j < 32; ++j) g += (havg[j] + hmax[j]) * w2[t * 32 + j];
  gate[t] = 1.0f / (1.0f + expf(-g));
}

__global__ __launch_bounds__(256) void sta_scale_k(float* __restrict__ xf,
                                                   const float* __restrict__ gate) {
  const size_t i = (size_t)(blockIdx.x * 256 + threadIdx.x) * 4;
  float4 v = *(const float4*)(xf + i);
  const float g = gate[i >> 15];
  v.x *= g; v.y *= g; v.z *= g; v.w *= g;
  *(float4*)(xf + i) = v;
}

extern "C" void kernel_launch(void* const* d_in, const int* in_sizes, int n_in,
                              void* d_out, int out_size, void* d_ws, size_t ws_size,
                              hipStream_t stream) {
  const float* x    = (const float*)d_in[0];   // (3,64,256,512)
  const float* hist = (const float*)d_in[1];   // (2,64,256,512)
  const float* td   = (const float*)d_in[4];   // (1,5)
  const float* ew   = (const float*)d_in[6];
  const float* eb   = (const float*)d_in[7];
  const float* b0w  = (const float*)d_in[8];
  const float* b0b  = (const float*)d_in[9];
  const float* b1w  = (const float*)d_in[10];
  const float* b1b  = (const float*)d_in[11];
  const float* b2w  = (const float*)d_in[12];
  const float* b2b  = (const float*)d_in[13];
  const float* d0w  = (const float*)d_in[14];
  const float* d0b  = (const float*)d_in[15];
  const float* d1w  = (const float*)d_in[16];
  const float* d1b  = (const float*)d_in[17];
  const float* d2w  = (const float*)d_in[18];
  const float* d2b  = (const float*)d_in[19];
  const float* w1   = (const float*)d_in[20];
  const float* w2   = (const float*)d_in[21];

  float* out = (float*)d_out;  // (512,128,256)
  float* ws  = (float*)d_ws;

  float* scales = ws + WS_SCALES;
  float* l0x = ws + WS_L0X;
  float* l1  = ws + WS_L1;
  float* l2  = ws + WS_L2;
  unsigned short* f1h = (unsigned short*)(ws + WS_F1);
  unsigned short* f2h = (unsigned short*)(ws + WS_F2);
  unsigned short* w0p = (unsigned short*)(ws + WS_W0P);
  unsigned short* w1p = (unsigned short*)(ws + WS_W1P);
  unsigned short* w2p = (unsigned short*)(ws + WS_W2P);
  unsigned short* u0p = (unsigned short*)(ws + WS_U0P);
  unsigned short* u1p = (unsigned short*)(ws + WS_U1P);
  unsigned short* u2p = (unsigned short*)(ws + WS_U2P);
  unsigned short* l0h = (unsigned short*)(ws + WS_L0H);
  unsigned short* l1h = (unsigned short*)(ws + WS_L1H);
  unsigned short* stg = (unsigned short*)(ws + WS_STG);  // serially reused

  pack_all_k<<<491, 256, 0, stream>>>(td, ew, eb, scales,
                                      b0w, w0p, b1w, w1p, b2w, w2p,
                                      d0w, u0p, d1w, u1p, d2w, u2p);

  // ---- level 0 on x (conv also emits NHWC bf16 l0h for conv1)
  repack_k<<<dim3(8, 256, 3), 256, 0, stream>>>(x, stg, 64, 256, 512);
  conv_mfma_k<64, 4><<<dim3(4, 128, 3), 256, 73728, stream>>>(
      stg, w0p, b0b, l0x, l0h, scales, 64, 128, 256, 1);

  // ---- level 0 on historical (stg reuse; stream-serial)
  repack_k<<<dim3(8, 256, 2), 256, 0, stream>>>(hist, stg, 64, 256, 512);
  conv_mfma_k<64, 4><<<dim3(4, 128, 2), 256, 73728, stream>>>(
      stg, w0p, b0b, out + (size_t)384 * HW0, nullptr, scales + 3, 64, 128, 256, 1);

  // ---- fused level-0 attention + 1x1 up
  fuse_up0_k<<<512, 256, 0, stream>>>(l0x, u0p, d0b, out);

  // ---- level 1 (conv emits l1h for conv2)
  conv_mfma_k<64, 4><<<dim3(2, 64, 6), 256, 73728, stream>>>(
      l0h, w1p, b1b, l1, l1h, nullptr, 128, 64, 128, 2);
  fuse2_k<128><<<256, 256, 0, stream>>>(l1, f1h, 8192, 0.0883883476f);
  up_mfma_k<128, 8, 1><<<dim3(128, 4), 256, 32768, stream>>>(
      f1h, u1p, d1b, out + (size_t)128 * HW0);

  // ---- level 2
  conv_mfma_k<128, 2><<<dim3(1, 32, 24), 256, 73728, stream>>>(
      l1h, w2p, b2b, l2, nullptr, nullptr, 256, 32, 64, 8);
  fuse2_k<256><<<128, 256, 0, stream>>>(l2, f2h, 2048, 0.0625f);
  up_mfma_k<256, 4, 2><<<dim3(32, 32), 256, 32768, stream>>>(
      f2h, u2p, d2b, out + (size_t)256 * HW0);

  // ---- STA gate
  sta_reduce_k<<<512, 256, 0, stream>>>(out, ws + WS_MEAN, ws + WS_MAX);
  sta_gate_k<<<1, 512, 0, stream>>>(ws + WS_MEAN, ws + WS_MAX, w1, w2, ws + WS_GATE);
  sta_scale_k<<<16384, 256, 0, stream>>>(out, ws + WS_GATE);
}